// Round 13
// baseline (6297.565 us; speedup 1.0000x reference)
//
#include <hip/hip_runtime.h>
#include <math.h>

#define B_ 32
#define N_ 1023
#define E_ 256
#define H_ 512
#define V_ 32000
#define T_ 64
#define NBL 250   // logits col-tiles (128 cols each)

__device__ __forceinline__ float sigf(float x) { return 1.0f / (1.0f + expf(-x)); }

__device__ __forceinline__ void nt_store4(float* p, float4 v)
{
    __builtin_nontemporal_store(v.x, p + 0);
    __builtin_nontemporal_store(v.y, p + 1);
    __builtin_nontemporal_store(v.z, p + 2);
    __builtin_nontemporal_store(v.w, p + 3);
}

// ---------------------------------------------------------------------------
// Tree iou GEMM (large levels): 128x128 tile, 8x8 micro.  [R5/R11 proven]
// ---------------------------------------------------------------------------
template<bool LEAF>
__global__ void __launch_bounds__(256)
iou_gemm_k(const int* __restrict__ node_feat, const int* __restrict__ mask,
           const float* __restrict__ emb, const float* __restrict__ Wiou,
           const float* __restrict__ Uiou, const float* __restrict__ hbuf,
           float* __restrict__ iou_out, int first, int n, int nshift)
{
    const int rows = B_ * n;
    const int K = LEAF ? E_ : (E_ + H_);
    const int rt = blockIdx.x, ct = blockIdx.y;
    const int tid = threadIdx.x;
    const int tr = tid >> 4, tc = tid & 15;

    __shared__ __align__(16) float As[8][136];
    __shared__ __align__(16) float Bs[8][136];

    float acc[8][8];
#pragma unroll
    for (int i = 0; i < 8; ++i)
#pragma unroll
        for (int j = 0; j < 8; ++j) acc[i][j] = 0.0f;

    const int lrow = tid >> 1;
    const int lkq  = (tid & 1) << 2;
    const int grow = rt * 128 + lrow;
    const bool rvalid = grow < rows;
    int tok = 0; float mval = 0.0f; int hoff1 = 0, hoff2 = 0;
    if (rvalid) {
        const int b = grow >> nshift, j = grow & (n - 1);
        const int node = first + j;
        tok  = node_feat[b * N_ + node];
        mval = (float)mask[b * N_ + node];
        if (!LEAF) {
            hoff1 = (b * N_ + 2 * node + 1) * H_;
            hoff2 = hoff1 + H_;
        }
    }
    const int bk   = tid >> 5;
    const int bcol = (tid & 31) << 2;
    const int gcol = ct * 128 + bcol;

    const int nkt = K >> 3;
    for (int kt = 0; kt < nkt; ++kt) {
        const int k0 = kt << 3;
        {
            const int kg = k0 + lkq;
            float4 v = make_float4(0.f, 0.f, 0.f, 0.f);
            if (rvalid) {
                if (LEAF || kg < E_) {
                    float4 e = *(const float4*)(emb + tok * E_ + kg);
                    v.x = e.x * mval; v.y = e.y * mval; v.z = e.z * mval; v.w = e.w * mval;
                } else {
                    const int kk = kg - E_;
                    float4 h1 = *(const float4*)(hbuf + hoff1 + kk);
                    float4 h2 = *(const float4*)(hbuf + hoff2 + kk);
                    v.x = h1.x + h2.x; v.y = h1.y + h2.y;
                    v.z = h1.z + h2.z; v.w = h1.w + h2.w;
                }
            }
            As[lkq + 0][lrow] = v.x;
            As[lkq + 1][lrow] = v.y;
            As[lkq + 2][lrow] = v.z;
            As[lkq + 3][lrow] = v.w;
        }
        {
            const int kg = k0 + bk;
            const float* src = (LEAF || kg < E_) ? (Wiou + kg * 1536 + gcol)
                                                 : (Uiou + (kg - E_) * 1536 + gcol);
            *(float4*)&Bs[bk][bcol] = *(const float4*)src;
        }
        __syncthreads();
#pragma unroll
        for (int kk = 0; kk < 8; ++kk) {
            float a[8], bb[8];
            *(float4*)&a[0]  = *(const float4*)&As[kk][tr << 3];
            *(float4*)&a[4]  = *(const float4*)&As[kk][(tr << 3) + 4];
            *(float4*)&bb[0] = *(const float4*)&Bs[kk][tc << 2];
            *(float4*)&bb[4] = *(const float4*)&Bs[kk][(tc << 2) + 64];
#pragma unroll
            for (int i = 0; i < 8; ++i)
#pragma unroll
                for (int j = 0; j < 8; ++j)
                    acc[i][j] = fmaf(a[i], bb[j], acc[i][j]);
        }
        __syncthreads();
    }
#pragma unroll
    for (int i = 0; i < 8; ++i) {
        const int r = rt * 128 + (tr << 3) + i;
        if (r < rows) {
            float* dst = iou_out + (size_t)r * 1536 + ct * 128;
            *(float4*)(dst + (tc << 2))      = make_float4(acc[i][0], acc[i][1], acc[i][2], acc[i][3]);
            *(float4*)(dst + 64 + (tc << 2)) = make_float4(acc[i][4], acc[i][5], acc[i][6], acc[i][7]);
        }
    }
}

// ---------------------------------------------------------------------------
// FUSED small-level iou GEMM + apply (internal, n<=64): 64 rows x 64 h-cols
// x 3 gates, 4x4 micro per gate. Same conflict-free LDS pattern as the
// proven iou_small_k; epilogue applies sigmoid/tanh in place (identical
// k-order and elementwise ops to iou_small_k + apply_node_k).
// ---------------------------------------------------------------------------
__global__ void __launch_bounds__(256)
iou_apply_small_k(const int* __restrict__ node_feat, const int* __restrict__ mask,
                  const float* __restrict__ emb, const float* __restrict__ Wiou,
                  const float* __restrict__ Uiou, const float* __restrict__ b_iou,
                  const float* __restrict__ cagg, float* __restrict__ hbuf,
                  float* __restrict__ cbuf, int first, int n, int nshift)
{
    const int rows = B_ * n;
    const int rt = blockIdx.x, ct = blockIdx.y;   // ct: 8 tiles of 64 h-cols
    const int tid = threadIdx.x;
    const int tr = tid >> 4, tc = tid & 15;

    __shared__ __align__(16) float As[8][72];
    __shared__ __align__(16) float Bs[3][8][72];

    float aI[4][4], aO[4][4], aU[4][4];
#pragma unroll
    for (int i = 0; i < 4; ++i)
#pragma unroll
        for (int j = 0; j < 4; ++j) { aI[i][j] = 0.f; aO[i][j] = 0.f; aU[i][j] = 0.f; }

    const int srow = tid & 63, skq = tid >> 6;
    const int grow = rt * 64 + srow;
    const bool rvalid = grow < rows;
    int tok = 0; float mval = 0.f; int hoff1 = 0, hoff2 = 0;
    if (rvalid) {
        const int b = grow >> nshift, j = grow & (n - 1);
        const int node = first + j;
        tok  = node_feat[b * N_ + node];
        mval = (float)mask[b * N_ + node];
        hoff1 = (b * N_ + 2 * node + 1) * H_;
        hoff2 = hoff1 + H_;
    }
    const int gcol = ct * 64 + srow;

    for (int kt = 0; kt < 96; ++kt) {
        const int k0 = kt << 3;
        {   // A (gathered, float2 per thread)
            const int kg = k0 + (skq << 1);
            float2 v = make_float2(0.f, 0.f);
            if (rvalid) {
                if (kg < E_) {
                    float2 e = *(const float2*)(emb + (size_t)tok * E_ + kg);
                    v.x = e.x * mval; v.y = e.y * mval;
                } else {
                    const int kk = kg - E_;
                    float2 h1 = *(const float2*)(hbuf + hoff1 + kk);
                    float2 h2 = *(const float2*)(hbuf + hoff2 + kk);
                    v.x = h1.x + h2.x; v.y = h1.y + h2.y;
                }
            }
            As[(skq << 1) + 0][srow] = v.x;
            As[(skq << 1) + 1][srow] = v.y;
        }
        {   // B: 2 rows x 3 gate strips (6 scalars/thread)
            const int kg = k0 + (skq << 1);
            const float* s0 = (kg < E_) ? (Wiou + (size_t)kg * 1536)
                                        : (Uiou + (size_t)(kg - E_) * 1536);
            const float* s1 = ((kg + 1) < E_) ? (Wiou + (size_t)(kg + 1) * 1536)
                                              : (Uiou + (size_t)(kg + 1 - E_) * 1536);
            Bs[0][(skq << 1) + 0][srow] = s0[gcol];
            Bs[0][(skq << 1) + 1][srow] = s1[gcol];
            Bs[1][(skq << 1) + 0][srow] = s0[512 + gcol];
            Bs[1][(skq << 1) + 1][srow] = s1[512 + gcol];
            Bs[2][(skq << 1) + 0][srow] = s0[1024 + gcol];
            Bs[2][(skq << 1) + 1][srow] = s1[1024 + gcol];
        }
        __syncthreads();
#pragma unroll
        for (int kk = 0; kk < 8; ++kk) {
            float a[4], bI[4], bO[4], bU[4];
            *(float4*)&a[0]  = *(const float4*)&As[kk][tr << 2];
            *(float4*)&bI[0] = *(const float4*)&Bs[0][kk][tc << 2];
            *(float4*)&bO[0] = *(const float4*)&Bs[1][kk][tc << 2];
            *(float4*)&bU[0] = *(const float4*)&Bs[2][kk][tc << 2];
#pragma unroll
            for (int i = 0; i < 4; ++i)
#pragma unroll
                for (int j = 0; j < 4; ++j) {
                    aI[i][j] = fmaf(a[i], bI[j], aI[i][j]);
                    aO[i][j] = fmaf(a[i], bO[j], aO[i][j]);
                    aU[i][j] = fmaf(a[i], bU[j], aU[i][j]);
                }
        }
        __syncthreads();
    }

    // ---- epilogue: apply_node in place ----
    const int cbase = ct * 64 + (tc << 2);
    float4 bi4 = *(const float4*)(b_iou + cbase);
    float4 bo4 = *(const float4*)(b_iou + 512 + cbase);
    float4 bu4 = *(const float4*)(b_iou + 1024 + cbase);
    const float bI[4] = { bi4.x, bi4.y, bi4.z, bi4.w };
    const float bO[4] = { bo4.x, bo4.y, bo4.z, bo4.w };
    const float bU[4] = { bu4.x, bu4.y, bu4.z, bu4.w };

#pragma unroll
    for (int p = 0; p < 4; ++p) {
        const int r = rt * 64 + (tr << 2) + p;
        if (r < rows) {
            const int b = r >> nshift, j = r & (n - 1);
            const int node = first + j;
            float4 ca = *(const float4*)(cagg + (size_t)r * H_ + cbase);
            float cn[4], hn[4];
            cn[0] = sigf(aI[p][0] + bI[0]) * tanhf(aU[p][0] + bU[0]) + ca.x;
            cn[1] = sigf(aI[p][1] + bI[1]) * tanhf(aU[p][1] + bU[1]) + ca.y;
            cn[2] = sigf(aI[p][2] + bI[2]) * tanhf(aU[p][2] + bU[2]) + ca.z;
            cn[3] = sigf(aI[p][3] + bI[3]) * tanhf(aU[p][3] + bU[3]) + ca.w;
#pragma unroll
            for (int e = 0; e < 4; ++e)
                hn[e] = sigf(aO[p][e] + bO[e]) * tanhf(cn[e]);
            const size_t o = (size_t)(b * N_ + node) * H_ + cbase;
            *(float4*)(cbuf + o) = make_float4(cn[0], cn[1], cn[2], cn[3]);
            *(float4*)(hbuf + o) = make_float4(hn[0], hn[1], hn[2], hn[3]);
        }
    }
}

// ---------------------------------------------------------------------------
// f-gate GEMM (large levels): 128x128 tile with fused c_agg epilogue.
// ---------------------------------------------------------------------------
__global__ void __launch_bounds__(256)
fagg_gemm_k(const float* __restrict__ hbuf, const float* __restrict__ cbuf,
            const float* __restrict__ Ufw, const float* __restrict__ Ufb,
            float* __restrict__ cagg, int first, int n, int nshift)
{
    const int rows = 64 * n;
    const int rt = blockIdx.x, ct = blockIdx.y;
    const int tid = threadIdx.x;
    const int tr = tid >> 4, tc = tid & 15;

    __shared__ __align__(16) float As[8][136];
    __shared__ __align__(16) float Bs[8][136];

    float acc[8][8];
#pragma unroll
    for (int i = 0; i < 8; ++i)
#pragma unroll
        for (int j = 0; j < 8; ++j) acc[i][j] = 0.0f;

    const int lrow = tid >> 1;
    const int lkq  = (tid & 1) << 2;
    const int grow = rt * 128 + lrow;
    const bool rvalid = grow < rows;
    int hoff = 0;
    if (rvalid) {
        const int bj = grow >> 1, s = grow & 1;
        const int b = bj >> nshift, j = bj & (n - 1);
        const int node = first + j;
        hoff = (b * N_ + 2 * node + 1 + s) * H_;
    }
    const int bk   = tid >> 5;
    const int bcol = (tid & 31) << 2;
    const int gcol = ct * 128 + bcol;

    for (int kt = 0; kt < 64; ++kt) {
        const int k0 = kt << 3;
        {
            const int kg = k0 + lkq;
            float4 v = make_float4(0.f, 0.f, 0.f, 0.f);
            if (rvalid) v = *(const float4*)(hbuf + hoff + kg);
            As[lkq + 0][lrow] = v.x;
            As[lkq + 1][lrow] = v.y;
            As[lkq + 2][lrow] = v.z;
            As[lkq + 3][lrow] = v.w;
        }
        {
            const int kg = k0 + bk;
            *(float4*)&Bs[bk][bcol] = *(const float4*)(Ufw + kg * H_ + gcol);
        }
        __syncthreads();
#pragma unroll
        for (int kk = 0; kk < 8; ++kk) {
            float a[8], bb[8];
            *(float4*)&a[0]  = *(const float4*)&As[kk][tr << 3];
            *(float4*)&a[4]  = *(const float4*)&As[kk][(tr << 3) + 4];
            *(float4*)&bb[0] = *(const float4*)&Bs[kk][tc << 2];
            *(float4*)&bb[4] = *(const float4*)&Bs[kk][(tc << 2) + 64];
#pragma unroll
            for (int i = 0; i < 8; ++i)
#pragma unroll
                for (int j = 0; j < 8; ++j)
                    acc[i][j] = fmaf(a[i], bb[j], acc[i][j]);
        }
        __syncthreads();
    }
#pragma unroll
    for (int p = 0; p < 4; ++p) {
        const int r0 = rt * 128 + (tr << 3) + 2 * p;
        if (r0 < rows) {
            const int bj = r0 >> 1;
            const int b = bj >> nshift, j = bj & (n - 1);
            const int node = first + j;
            const float* c1 = cbuf + (b * N_ + 2 * node + 1) * H_ + ct * 128;
            const float* c2 = c1 + H_;
            float* dst = cagg + bj * H_ + ct * 128;
#pragma unroll
            for (int g = 0; g < 2; ++g) {
                const int off = (g ? 64 : 0) + (tc << 2);
                const int jb = g * 4;
                float4 cc1 = *(const float4*)(c1 + off);
                float4 cc2 = *(const float4*)(c2 + off);
                float4 bbv = *(const float4*)(Ufb + ct * 128 + off);
                float4 res;
                res.x = sigf(acc[2*p][jb+0] + bbv.x) * cc1.x + sigf(acc[2*p+1][jb+0] + bbv.x) * cc2.x;
                res.y = sigf(acc[2*p][jb+1] + bbv.y) * cc1.y + sigf(acc[2*p+1][jb+1] + bbv.y) * cc2.y;
                res.z = sigf(acc[2*p][jb+2] + bbv.z) * cc1.z + sigf(acc[2*p+1][jb+2] + bbv.z) * cc2.z;
                res.w = sigf(acc[2*p][jb+3] + bbv.w) * cc1.w + sigf(acc[2*p+1][jb+3] + bbv.w) * cc2.w;
                *(float4*)(dst + off) = res;
            }
        }
    }
}

// ---------------------------------------------------------------------------
// f-gate GEMM (small levels, n<=64): 64x64 tile, 4x4 micro, fused epilogue.
// ---------------------------------------------------------------------------
__global__ void __launch_bounds__(256)
fagg_small_k(const float* __restrict__ hbuf, const float* __restrict__ cbuf,
             const float* __restrict__ Ufw, const float* __restrict__ Ufb,
             float* __restrict__ cagg, int first, int n, int nshift)
{
    const int rows = 64 * n;
    const int rt = blockIdx.x, ct = blockIdx.y;
    const int tid = threadIdx.x;
    const int tr = tid >> 4, tc = tid & 15;

    __shared__ __align__(16) float As[8][72];
    __shared__ __align__(16) float Bs[8][72];

    float acc[4][4];
#pragma unroll
    for (int i = 0; i < 4; ++i)
#pragma unroll
        for (int j = 0; j < 4; ++j) acc[i][j] = 0.0f;

    const int srow = tid & 63, skq = tid >> 6;
    const int grow = rt * 64 + srow;
    const bool rvalid = grow < rows;
    int hoff = 0;
    if (rvalid) {
        const int bj = grow >> 1, s = grow & 1;
        const int b = bj >> nshift, j = bj & (n - 1);
        const int node = first + j;
        hoff = (b * N_ + 2 * node + 1 + s) * H_;
    }
    const int gcol = ct * 64 + srow;

    for (int kt = 0; kt < 64; ++kt) {
        const int k0 = kt << 3;
        {
            const int kg = k0 + (skq << 1);
            float2 v = make_float2(0.f, 0.f);
            if (rvalid) v = *(const float2*)(hbuf + hoff + kg);
            As[(skq << 1) + 0][srow] = v.x;
            As[(skq << 1) + 1][srow] = v.y;
        }
        {
            const int kg = k0 + (skq << 1);
            Bs[(skq << 1) + 0][srow] = Ufw[(size_t)kg * H_ + gcol];
            Bs[(skq << 1) + 1][srow] = Ufw[(size_t)(kg + 1) * H_ + gcol];
        }
        __syncthreads();
#pragma unroll
        for (int kk = 0; kk < 8; ++kk) {
            float a[4], bb[4];
            *(float4*)&a[0]  = *(const float4*)&As[kk][tr << 2];
            *(float4*)&bb[0] = *(const float4*)&Bs[kk][tc << 2];
#pragma unroll
            for (int i = 0; i < 4; ++i)
#pragma unroll
                for (int j = 0; j < 4; ++j)
                    acc[i][j] = fmaf(a[i], bb[j], acc[i][j]);
        }
        __syncthreads();
    }
#pragma unroll
    for (int p = 0; p < 2; ++p) {
        const int r0 = rt * 64 + (tr << 2) + 2 * p;
        if (r0 < rows) {
            const int bj = r0 >> 1;
            const int b = bj >> nshift, j = bj & (n - 1);
            const int node = first + j;
            const float* c1 = cbuf + (b * N_ + 2 * node + 1) * H_ + ct * 64;
            const float* c2 = c1 + H_;
            float* dst = cagg + bj * H_ + ct * 64;
            const int off = tc << 2;
            float4 cc1 = *(const float4*)(c1 + off);
            float4 cc2 = *(const float4*)(c2 + off);
            float4 bbv = *(const float4*)(Ufb + ct * 64 + off);
            float4 res;
            res.x = sigf(acc[2*p][0] + bbv.x) * cc1.x + sigf(acc[2*p+1][0] + bbv.x) * cc2.x;
            res.y = sigf(acc[2*p][1] + bbv.y) * cc1.y + sigf(acc[2*p+1][1] + bbv.y) * cc2.y;
            res.z = sigf(acc[2*p][2] + bbv.z) * cc1.z + sigf(acc[2*p+1][2] + bbv.z) * cc2.z;
            res.w = sigf(acc[2*p][3] + bbv.w) * cc1.w + sigf(acc[2*p+1][3] + bbv.w) * cc2.w;
            *(float4*)(dst + off) = res;
        }
    }
}

// ---------------------------------------------------------------------------
// apply_node for large levels (n>=128) + leaves
// ---------------------------------------------------------------------------
template<bool LEAF>
__global__ void apply_node_k(const float* __restrict__ iou,
                             const float* __restrict__ b_iou,
                             const float* __restrict__ cagg,
                             float* __restrict__ hbuf, float* __restrict__ cbuf,
                             int first, int n, int nshift)
{
    const int gid = blockIdx.x * 256 + threadIdx.x;
    if (gid >= B_ * n * 128) return;
    const int r = gid >> 7, col = (gid & 127) << 2;
    const float* row = iou + (size_t)r * 1536;
    float4 iv = *(const float4*)(row + col);
    float4 ov = *(const float4*)(row + 512 + col);
    float4 uv = *(const float4*)(row + 1024 + col);
    float4 bi = *(const float4*)(b_iou + col);
    float4 bo = *(const float4*)(b_iou + 512 + col);
    float4 bu = *(const float4*)(b_iou + 1024 + col);
    float4 ca = make_float4(0.f, 0.f, 0.f, 0.f);
    if (!LEAF) ca = *(const float4*)(cagg + r * H_ + col);
    float4 cn, hn;
    cn.x = sigf(iv.x + bi.x) * tanhf(uv.x + bu.x) + ca.x;
    cn.y = sigf(iv.y + bi.y) * tanhf(uv.y + bu.y) + ca.y;
    cn.z = sigf(iv.z + bi.z) * tanhf(uv.z + bu.z) + ca.z;
    cn.w = sigf(iv.w + bi.w) * tanhf(uv.w + bu.w) + ca.w;
    hn.x = sigf(ov.x + bo.x) * tanhf(cn.x);
    hn.y = sigf(ov.y + bo.y) * tanhf(cn.y);
    hn.z = sigf(ov.z + bo.z) * tanhf(cn.z);
    hn.w = sigf(ov.w + bo.w) * tanhf(cn.w);
    const int b = r >> nshift, j = r & (n - 1);
    const int node = first + j;
    const size_t o = (size_t)(b * N_ + node) * H_ + col;
    *(float4*)(cbuf + o) = cn;
    *(float4*)(hbuf + o) = hn;
}

// ---------------------------------------------------------------------------
// two-stage mean over nodes
// ---------------------------------------------------------------------------
__global__ void mean_part_k(const float* __restrict__ hbuf, float* __restrict__ mpart)
{
    const int bid = blockIdx.x;               // 256 = 32 b x 8 chunks
    const int b = bid >> 3, chunk = bid & 7;
    const int tid = threadIdx.x;
    const int n0 = chunk * 128;
    const int n1 = (n0 + 128 < N_) ? (n0 + 128) : N_;
    float s0 = 0.f, s1 = 0.f;
    for (int nn = n0; nn < n1; ++nn) {
        const float* p = hbuf + (size_t)(b * N_ + nn) * H_;
        s0 += p[tid];
        s1 += p[tid + 256];
    }
    mpart[(bid << 9) + tid]       = s0;
    mpart[(bid << 9) + tid + 256] = s1;
}

__global__ void mean_fin_k(const float* __restrict__ mpart, float* __restrict__ mf)
{
    const int gid = blockIdx.x * 256 + threadIdx.x;   // 16384
    const int b = gid >> 9, k = gid & 511;
    float s = 0.f;
#pragma unroll
    for (int c = 0; c < 8; ++c) s += mpart[(((b << 3) + c) << 9) + k];
    mf[gid] = s * (1.0f / 1023.0f);
}

__global__ void hidcel_k(const float* __restrict__ mf,
                         const float* __restrict__ hw, const float* __restrict__ hb,
                         const float* __restrict__ cw, const float* __restrict__ cb,
                         float* __restrict__ hs0, float* __restrict__ cs)
{
    const int gid = blockIdx.x * 256 + threadIdx.x;   // 32768
    const int which = gid >> 14;
    const int b = (gid >> 9) & 31, l = gid & 511;
    const float* W = which ? cw : hw;
    float acc = which ? cb[l] : hb[l];
#pragma unroll 8
    for (int k = 0; k < H_; ++k) acc = fmaf(mf[b * H_ + k], W[k * H_ + l], acc);
    if (which) cs[b * H_ + l] = acc; else hs0[b * H_ + l] = acc;
}

// ---------------------------------------------------------------------------
// gate-weight transpose: Wt[g][k] (g in [0,2048), k in [0,768))
// ---------------------------------------------------------------------------
__global__ void __launch_bounds__(256)
wtrans_k(const float* __restrict__ W_ih, const float* __restrict__ W_hh,
         float* __restrict__ Wt)
{
    __shared__ float t[64][33];
    const int k0 = blockIdx.x * 32;   // 24 k-tiles
    const int g0 = blockIdx.y * 64;   // 32 g-tiles
    const int tid = threadIdx.x;
    for (int idx = tid; idx < 2048; idx += 256) {
        const int kk = idx >> 6, gg = idx & 63;
        const int k = k0 + kk;
        t[gg][kk] = (k < E_) ? W_ih[(size_t)k * 2048 + g0 + gg]
                             : W_hh[(size_t)(k - E_) * 2048 + g0 + gg];
    }
    __syncthreads();
    for (int idx = tid; idx < 2048; idx += 256) {
        const int gg = idx >> 5, kk = idx & 31;
        Wt[(size_t)(g0 + gg) * 768 + k0 + kk] = t[gg][kk];
    }
}

// ---------------------------------------------------------------------------
// decoder LSTM step v6 (R11 proven): transposed Wt, float4 k-sweeps.
// ---------------------------------------------------------------------------
__global__ void __launch_bounds__(256)
lstm_step_k(const float* __restrict__ emb, const float* __restrict__ Wt,
            const float* __restrict__ b_ih, const float* __restrict__ b_hh,
            const float* __restrict__ pval, const int* __restrict__ pidx,
            const float* __restrict__ hs_in, float* __restrict__ hs_out,
            float* __restrict__ cs, int t)
{
    __shared__ __align__(16) float xh[8][776];       // 24.8 KB
    __shared__ __align__(16) float part[4][8][8][4]; // 4 KB
    __shared__ float rv[256];
    __shared__ int   ri[256];
    __shared__ int   tokS[8];
    const int tid = threadIdx.x;
    const int bg  = blockIdx.y;          // b-group (8 batches)

    if (t == 1) {
        if (tid < 8) tokS[tid] = 0;
    } else {
        const int bs = tid >> 5, th = tid & 31;     // 8 b x 32 scanners
        const int b = bg * 8 + bs;
        float bv = -INFINITY; int bi = 0x7fffffff;
        for (int p = th; p < NBL; p += 32) {
            const float v = pval[b * NBL + p];
            const int  ix = pidx[b * NBL + p];
            if (v > bv || (v == bv && ix < bi)) { bv = v; bi = ix; }
        }
        rv[tid] = bv; ri[tid] = bi;
        __syncthreads();
        if (tid < 8) {
            float Bv = -INFINITY; int Bi = 0x7fffffff;
#pragma unroll
            for (int c = 0; c < 32; ++c) {
                const float v = rv[tid * 32 + c];
                const int  ix = ri[tid * 32 + c];
                if (v > Bv || (v == Bv && ix < Bi)) { Bv = v; Bi = ix; }
            }
            tokS[tid] = Bi;
        }
    }
    __syncthreads();

    for (int idx = tid; idx < 8 * E_; idx += 256) {
        const int b = idx >> 8, k = idx & 255;
        xh[b][k] = emb[(size_t)tokS[b] * E_ + k];
    }
    for (int idx = tid; idx < 8 * H_; idx += 256) {
        const int b = idx >> 9, k = idx & 511;
        xh[b][E_ + k] = hs_in[(size_t)(bg * 8 + b) * H_ + k];
    }
    __syncthreads();

    const int ks = tid >> 6;
    const int lane = tid & 63;
    const int bi = lane >> 3, li = lane & 7;
    const int l = blockIdx.x * 8 + li;
    float ai = 0.f, af = 0.f, ag = 0.f, ao = 0.f;
    const int k0 = ks * 192;
    const float* wi = Wt + (size_t)(l)        * 768 + k0;
    const float* wf = Wt + (size_t)(512 + l)  * 768 + k0;
    const float* wg = Wt + (size_t)(1024 + l) * 768 + k0;
    const float* wo = Wt + (size_t)(1536 + l) * 768 + k0;
    const float* xp = &xh[bi][k0];
#pragma unroll 4
    for (int kk = 0; kk < 192; kk += 4) {
        const float4 xv = *(const float4*)(xp + kk);
        const float4 w0 = *(const float4*)(wi + kk);
        const float4 w1 = *(const float4*)(wf + kk);
        const float4 w2 = *(const float4*)(wg + kk);
        const float4 w3 = *(const float4*)(wo + kk);
        ai = fmaf(xv.x, w0.x, ai); ai = fmaf(xv.y, w0.y, ai);
        ai = fmaf(xv.z, w0.z, ai); ai = fmaf(xv.w, w0.w, ai);
        af = fmaf(xv.x, w1.x, af); af = fmaf(xv.y, w1.y, af);
        af = fmaf(xv.z, w1.z, af); af = fmaf(xv.w, w1.w, af);
        ag = fmaf(xv.x, w2.x, ag); ag = fmaf(xv.y, w2.y, ag);
        ag = fmaf(xv.z, w2.z, ag); ag = fmaf(xv.w, w2.w, ag);
        ao = fmaf(xv.x, w3.x, ao); ao = fmaf(xv.y, w3.y, ao);
        ao = fmaf(xv.z, w3.z, ao); ao = fmaf(xv.w, w3.w, ao);
    }
    part[ks][bi][li][0] = ai;
    part[ks][bi][li][1] = af;
    part[ks][bi][li][2] = ag;
    part[ks][bi][li][3] = ao;
    __syncthreads();

    if (tid < 64) {
        const int b2 = tid >> 3, l2i = tid & 7;
        const int l2 = blockIdx.x * 8 + l2i;
        const int b = bg * 8 + b2;
        float s0 = 0.f, s1 = 0.f, s2 = 0.f, s3 = 0.f;
#pragma unroll
        for (int q = 0; q < 4; ++q) {
            s0 += part[q][b2][l2i][0];
            s1 += part[q][b2][l2i][1];
            s2 += part[q][b2][l2i][2];
            s3 += part[q][b2][l2i][3];
        }
        const float gi = s0 + b_ih[l2]        + b_hh[l2];
        const float gf = s1 + b_ih[512 + l2]  + b_hh[512 + l2];
        const float gg = s2 + b_ih[1024 + l2] + b_hh[1024 + l2];
        const float go = s3 + b_ih[1536 + l2] + b_hh[1536 + l2];
        const float co = cs[b * H_ + l2];
        const float cn = sigf(gf) * co + sigf(gi) * tanhf(gg);
        cs[b * H_ + l2] = cn;
        hs_out[b * H_ + l2] = sigf(go) * tanhf(cn);
    }
}

// ---------------------------------------------------------------------------
// logits partial: grid (250 col-tiles, 2 k-halves). [R5 proven]
// ---------------------------------------------------------------------------
__global__ void __launch_bounds__(256)
logits_part_k(const float* __restrict__ fc_w, const float* __restrict__ hs,
              float* __restrict__ partial)
{
    __shared__ __align__(16) float sm[256 * 36];   // 36,864 B
    const int tid = threadIdx.x;
    const int blk = blockIdx.x;       // col tile (128 cols)
    const int kh  = blockIdx.y;       // k half (256 rows)

    for (int idx = tid; idx < B_ * 256; idx += 256) {
        const int b = idx & 31, k = idx >> 5;
        sm[k * 36 + b] = hs[b * H_ + kh * 256 + k];
    }
    __syncthreads();

    const int w8   = (tid >> 6) << 3;       // wave's b-chunk: 0,8,16,24
    const int lane = tid & 63;
    const int col  = (blk << 7) + (lane << 1);

    float acc[8][2];
#pragma unroll
    for (int i = 0; i < 8; ++i) { acc[i][0] = 0.f; acc[i][1] = 0.f; }

    const float* wp = fc_w + (size_t)(kh * 256) * V_ + col;
    const float* hp = sm + w8;
    float2 wreg[8];
#pragma unroll
    for (int j = 0; j < 8; ++j) wreg[j] = *(const float2*)(wp + (size_t)j * V_);
    for (int kb = 0; kb < 32; ++kb) {
        float2 wnxt[8];
        if (kb < 31) {
            const float* wq = wp + (size_t)((kb + 1) << 3) * V_;
#pragma unroll
            for (int j = 0; j < 8; ++j) wnxt[j] = *(const float2*)(wq + (size_t)j * V_);
        }
#pragma unroll
        for (int j = 0; j < 8; ++j) {
            const float* hq = hp + ((kb << 3) + j) * 36;   // wave-uniform LDS broadcast
            float hv[8];
            *(float4*)&hv[0] = *(const float4*)(hq);
            *(float4*)&hv[4] = *(const float4*)(hq + 4);
#pragma unroll
            for (int i = 0; i < 8; ++i) {
                acc[i][0] = fmaf(hv[i], wreg[j].x, acc[i][0]);
                acc[i][1] = fmaf(hv[i], wreg[j].y, acc[i][1]);
            }
        }
        if (kb < 31) {
#pragma unroll
            for (int j = 0; j < 8; ++j) wreg[j] = wnxt[j];
        }
    }
#pragma unroll
    for (int i = 0; i < 8; ++i) {
        float* dst = partial + (size_t)(kh * B_ + w8 + i) * V_ + col;
        *(float2*)dst = make_float2(acc[i][0], acc[i][1]);
    }
}

// ---------------------------------------------------------------------------
// logits finalize: 250 blocks. sum 2 halves + bias -> out (NT stores),
// block argmax.
// ---------------------------------------------------------------------------
__global__ void __launch_bounds__(256)
logits_fin_k(const float* __restrict__ partial, const float* __restrict__ fc_b,
             float* __restrict__ out_t, float* __restrict__ pval,
             int* __restrict__ pidx)
{
    __shared__ float rv[256];
    __shared__ int   ri[256];
    const int tid = threadIdx.x, blk = blockIdx.x;
    const int b = tid >> 3, cg = (tid & 7) << 4;
    const int colbase = (blk << 7) + cg;

    const float* p0 = partial + (size_t)b * V_ + colbase;
    const float* p1 = partial + (size_t)(B_ + b) * V_ + colbase;
    const float* bp = fc_b + colbase;
    float* op = out_t + (size_t)b * V_ + colbase;

    float bv = -INFINITY; int bi = 0;
#pragma unroll
    for (int q = 0; q < 4; ++q) {
        float4 a = *(const float4*)(p0 + (q << 2));
        float4 c = *(const float4*)(p1 + (q << 2));
        float4 d = *(const float4*)(bp + (q << 2));
        float4 v;
        v.x = a.x + c.x + d.x; v.y = a.y + c.y + d.y;
        v.z = a.z + c.z + d.z; v.w = a.w + c.w + d.w;
        nt_store4(op + (q << 2), v);   // keep fc_w L3-resident
        const int c0 = cg + (q << 2);
        if (v.x > bv) { bv = v.x; bi = c0 + 0; }
        if (v.y > bv) { bv = v.y; bi = c0 + 1; }
        if (v.z > bv) { bv = v.z; bi = c0 + 2; }
        if (v.w > bv) { bv = v.w; bi = c0 + 3; }
    }
    rv[tid] = bv; ri[tid] = bi;
    __syncthreads();
    if (tid < B_) {
        float Bv = -INFINITY; int Bi = 0;
#pragma unroll
        for (int q = 0; q < 8; ++q) {
            const float v = rv[(tid << 3) + q];     // ascending col order
            if (v > Bv) { Bv = v; Bi = ri[(tid << 3) + q]; }
        }
        pval[tid * NBL + blk] = Bv;
        pidx[tid * NBL + blk] = (blk << 7) + Bi;
    }
}

// ---------------------------------------------------------------------------
extern "C" void kernel_launch(void* const* d_in, const int* in_sizes, int n_in,
                              void* d_out, int out_size, void* d_ws, size_t ws_size,
                              hipStream_t stream)
{
    (void)in_sizes; (void)n_in; (void)out_size; (void)ws_size;
    const int*   node_feat = (const int*)  d_in[0];
    const int*   mask      = (const int*)  d_in[1];
    const float* emb       = (const float*)d_in[2];
    const float* W_iou     = (const float*)d_in[3];
    const float* U_iou     = (const float*)d_in[4];
    const float* b_iou     = (const float*)d_in[5];
    const float* U_f_w     = (const float*)d_in[6];
    const float* U_f_b     = (const float*)d_in[7];
    const float* hid_fc_w  = (const float*)d_in[8];
    const float* hid_fc_b  = (const float*)d_in[9];
    const float* cell_fc_w = (const float*)d_in[10];
    const float* cell_fc_b = (const float*)d_in[11];
    const float* W_ih      = (const float*)d_in[12];
    const float* W_hh      = (const float*)d_in[13];
    const float* b_ih      = (const float*)d_in[14];
    const float* b_hh      = (const float*)d_in[15];
    const float* fc_w      = (const float*)d_in[16];
    const float* fc_b      = (const float*)d_in[17];
    float* out = (float*)d_out;

    float* ws      = (float*)d_ws;
    float* iou_buf = ws;                      // 12,582,912 (8192 x 1536) tree large levels
    float* cagg    = ws + 12582912;           //  4,194,304
    float* hbuf    = ws + 16777216;           // 16,760,832
    float* cbuf    = ws + 33538048;           // 16,760,832
    float* mf      = ws + 50298880;           //     16,384
    float* hsb     = ws + 50315264;           //     32,768 (ping-pong)
    float* csb     = ws + 50348032;           //     16,384
    float* pval    = ws + 50364416;           //      8,000 (32 x 250)
    int*   pidx    = (int*)(ws + 50372416);   //      8,000
    // after the tree, iou_buf is dead -> reuse
    float* mpart   = iou_buf;                 //    131,072 floats
    float* partial = iou_buf + 262144;        //  2,048,000 floats (2 x 32 x V)
    float* Wt      = iou_buf + 2359296;       //  1,572,864 floats (2048 x 768)

    // ---- tree: leaves (2 chunks of 256 nodes) ----
    for (int chunk = 0; chunk < 2; ++chunk) {
        const int first = 511 + 256 * chunk;
        dim3 g(64, 12);
        iou_gemm_k<true><<<g, 256, 0, stream>>>(node_feat, mask, emb, W_iou, U_iou,
                                                hbuf, iou_buf, first, 256, 8);
        apply_node_k<true><<<4096, 256, 0, stream>>>(iou_buf, b_iou, cagg,
                                                     hbuf, cbuf, first, 256, 8);
    }
    // ---- tree: internal levels ----
    for (int d = 8; d >= 0; --d) {
        const int n = 1 << d, first = n - 1;
        if (n <= 64) {
            dim3 gf((64 * n + 63) / 64, 8);
            fagg_small_k<<<gf, 256, 0, stream>>>(hbuf, cbuf, U_f_w, U_f_b, cagg, first, n, d);
            dim3 gi((32 * n + 63) / 64, 8);
            iou_apply_small_k<<<gi, 256, 0, stream>>>(node_feat, mask, emb, W_iou, U_iou,
                                                      b_iou, cagg, hbuf, cbuf, first, n, d);
        } else {
            dim3 gf((64 * n + 127) / 128, 4);
            fagg_gemm_k<<<gf, 256, 0, stream>>>(hbuf, cbuf, U_f_w, U_f_b, cagg, first, n, d);
            dim3 gi((32 * n + 127) / 128, 12);
            iou_gemm_k<false><<<gi, 256, 0, stream>>>(node_feat, mask, emb, W_iou, U_iou,
                                                      hbuf, iou_buf, first, n, d);
            apply_node_k<false><<<16 * n, 256, 0, stream>>>(iou_buf, b_iou, cagg,
                                                            hbuf, cbuf, first, n, d);
        }
    }
    // ---- pool + init + gate-weight transpose (iou_buf dead from here) ----
    mean_part_k<<<256, 256, 0, stream>>>(hbuf, mpart);
    mean_fin_k<<<64, 256, 0, stream>>>(mpart, mf);
    hidcel_k<<<128, 256, 0, stream>>>(mf, hid_fc_w, hid_fc_b, cell_fc_w, cell_fc_b, hsb, csb);
    dim3 gw(24, 32);
    wtrans_k<<<gw, 256, 0, stream>>>(W_ih, W_hh, Wt);
    // ---- out[0] = 0 ----
    hipMemsetAsync(d_out, 0, (size_t)B_ * V_ * sizeof(float), stream);
    // ---- decoder: 3 kernels per step ----
    for (int t = 1; t < T_; ++t) {
        const float* hs_in  = hsb + ((t - 1) & 1) * (B_ * H_);
        float*       hs_out = hsb + (t & 1) * (B_ * H_);
        dim3 gl(64, 4);
        lstm_step_k<<<gl, 256, 0, stream>>>(emb, Wt, b_ih, b_hh,
                                            pval, pidx, hs_in, hs_out, csb, t);
        dim3 gp(NBL, 2);
        logits_part_k<<<gp, 256, 0, stream>>>(fc_w, hs_out, partial);
        logits_fin_k<<<NBL, 256, 0, stream>>>(partial, fc_b,
                                              out + (size_t)t * B_ * V_, pval, pidx);
    }
}

// Round 14
// 5910.850 us; speedup vs baseline: 1.0654x; 1.0654x over previous
//
#include <hip/hip_runtime.h>
#include <math.h>

#define B_ 32
#define N_ 1023
#define E_ 256
#define H_ 512
#define V_ 32000
#define T_ 64
#define NBL 250   // logits col-tiles (128 cols each)

__device__ __forceinline__ float sigf(float x) { return 1.0f / (1.0f + expf(-x)); }

__device__ __forceinline__ void nt_store4(float* p, float4 v)
{
    __builtin_nontemporal_store(v.x, p + 0);
    __builtin_nontemporal_store(v.y, p + 1);
    __builtin_nontemporal_store(v.z, p + 2);
    __builtin_nontemporal_store(v.w, p + 3);
}

// ===========================================================================
// Tree GEMM bodies (byte-identical math to R11 kernels; rt/ct are params)
// ===========================================================================

// ---- iou body (128x128 tile, 8x8 micro); LDS [8][136] x2 ----
template<bool LEAF>
__device__ __forceinline__ void iou_body(
    const int* __restrict__ node_feat, const int* __restrict__ mask,
    const float* __restrict__ emb, const float* __restrict__ Wiou,
    const float* __restrict__ Uiou, const float* __restrict__ hbuf,
    float* __restrict__ iou_out, int first, int n, int nshift,
    int rt, int ct, float (*As)[136], float (*Bs)[136])
{
    const int rows = B_ * n;
    const int K = LEAF ? E_ : (E_ + H_);
    const int tid = threadIdx.x;
    const int tr = tid >> 4, tc = tid & 15;

    float acc[8][8];
#pragma unroll
    for (int i = 0; i < 8; ++i)
#pragma unroll
        for (int j = 0; j < 8; ++j) acc[i][j] = 0.0f;

    const int lrow = tid >> 1;
    const int lkq  = (tid & 1) << 2;
    const int grow = rt * 128 + lrow;
    const bool rvalid = grow < rows;
    int tok = 0; float mval = 0.0f; int hoff1 = 0, hoff2 = 0;
    if (rvalid) {
        const int b = grow >> nshift, j = grow & (n - 1);
        const int node = first + j;
        tok  = node_feat[b * N_ + node];
        mval = (float)mask[b * N_ + node];
        if (!LEAF) {
            hoff1 = (b * N_ + 2 * node + 1) * H_;
            hoff2 = hoff1 + H_;
        }
    }
    const int bk   = tid >> 5;
    const int bcol = (tid & 31) << 2;
    const int gcol = ct * 128 + bcol;

    const int nkt = K >> 3;
    for (int kt = 0; kt < nkt; ++kt) {
        const int k0 = kt << 3;
        {
            const int kg = k0 + lkq;
            float4 v = make_float4(0.f, 0.f, 0.f, 0.f);
            if (rvalid) {
                if (LEAF || kg < E_) {
                    float4 e = *(const float4*)(emb + tok * E_ + kg);
                    v.x = e.x * mval; v.y = e.y * mval; v.z = e.z * mval; v.w = e.w * mval;
                } else {
                    const int kk = kg - E_;
                    float4 h1 = *(const float4*)(hbuf + hoff1 + kk);
                    float4 h2 = *(const float4*)(hbuf + hoff2 + kk);
                    v.x = h1.x + h2.x; v.y = h1.y + h2.y;
                    v.z = h1.z + h2.z; v.w = h1.w + h2.w;
                }
            }
            As[lkq + 0][lrow] = v.x;
            As[lkq + 1][lrow] = v.y;
            As[lkq + 2][lrow] = v.z;
            As[lkq + 3][lrow] = v.w;
        }
        {
            const int kg = k0 + bk;
            const float* src = (LEAF || kg < E_) ? (Wiou + kg * 1536 + gcol)
                                                 : (Uiou + (kg - E_) * 1536 + gcol);
            *(float4*)&Bs[bk][bcol] = *(const float4*)src;
        }
        __syncthreads();
#pragma unroll
        for (int kk = 0; kk < 8; ++kk) {
            float a[8], bb[8];
            *(float4*)&a[0]  = *(const float4*)&As[kk][tr << 3];
            *(float4*)&a[4]  = *(const float4*)&As[kk][(tr << 3) + 4];
            *(float4*)&bb[0] = *(const float4*)&Bs[kk][tc << 2];
            *(float4*)&bb[4] = *(const float4*)&Bs[kk][(tc << 2) + 64];
#pragma unroll
            for (int i = 0; i < 8; ++i)
#pragma unroll
                for (int j = 0; j < 8; ++j)
                    acc[i][j] = fmaf(a[i], bb[j], acc[i][j]);
        }
        __syncthreads();
    }
#pragma unroll
    for (int i = 0; i < 8; ++i) {
        const int r = rt * 128 + (tr << 3) + i;
        if (r < rows) {
            float* dst = iou_out + (size_t)r * 1536 + ct * 128;
            *(float4*)(dst + (tc << 2))      = make_float4(acc[i][0], acc[i][1], acc[i][2], acc[i][3]);
            *(float4*)(dst + 64 + (tc << 2)) = make_float4(acc[i][4], acc[i][5], acc[i][6], acc[i][7]);
        }
    }
}

// ---- fagg body (128x128 tile, fused c_agg epilogue); LDS [8][136] x2 ----
__device__ __forceinline__ void fagg_body(
    const float* __restrict__ hbuf, const float* __restrict__ cbuf,
    const float* __restrict__ Ufw, const float* __restrict__ Ufb,
    float* __restrict__ cagg, int first, int n, int nshift,
    int rt, int ct, float (*As)[136], float (*Bs)[136])
{
    const int rows = 64 * n;
    const int tid = threadIdx.x;
    const int tr = tid >> 4, tc = tid & 15;

    float acc[8][8];
#pragma unroll
    for (int i = 0; i < 8; ++i)
#pragma unroll
        for (int j = 0; j < 8; ++j) acc[i][j] = 0.0f;

    const int lrow = tid >> 1;
    const int lkq  = (tid & 1) << 2;
    const int grow = rt * 128 + lrow;
    const bool rvalid = grow < rows;
    int hoff = 0;
    if (rvalid) {
        const int bj = grow >> 1, s = grow & 1;
        const int b = bj >> nshift, j = bj & (n - 1);
        const int node = first + j;
        hoff = (b * N_ + 2 * node + 1 + s) * H_;
    }
    const int bk   = tid >> 5;
    const int bcol = (tid & 31) << 2;
    const int gcol = ct * 128 + bcol;

    for (int kt = 0; kt < 64; ++kt) {
        const int k0 = kt << 3;
        {
            const int kg = k0 + lkq;
            float4 v = make_float4(0.f, 0.f, 0.f, 0.f);
            if (rvalid) v = *(const float4*)(hbuf + hoff + kg);
            As[lkq + 0][lrow] = v.x;
            As[lkq + 1][lrow] = v.y;
            As[lkq + 2][lrow] = v.z;
            As[lkq + 3][lrow] = v.w;
        }
        {
            const int kg = k0 + bk;
            *(float4*)&Bs[bk][bcol] = *(const float4*)(Ufw + kg * H_ + gcol);
        }
        __syncthreads();
#pragma unroll
        for (int kk = 0; kk < 8; ++kk) {
            float a[8], bb[8];
            *(float4*)&a[0]  = *(const float4*)&As[kk][tr << 3];
            *(float4*)&a[4]  = *(const float4*)&As[kk][(tr << 3) + 4];
            *(float4*)&bb[0] = *(const float4*)&Bs[kk][tc << 2];
            *(float4*)&bb[4] = *(const float4*)&Bs[kk][(tc << 2) + 64];
#pragma unroll
            for (int i = 0; i < 8; ++i)
#pragma unroll
                for (int j = 0; j < 8; ++j)
                    acc[i][j] = fmaf(a[i], bb[j], acc[i][j]);
        }
        __syncthreads();
    }
#pragma unroll
    for (int p = 0; p < 4; ++p) {
        const int r0 = rt * 128 + (tr << 3) + 2 * p;
        if (r0 < rows) {
            const int bj = r0 >> 1;
            const int b = bj >> nshift, j = bj & (n - 1);
            const int node = first + j;
            const float* c1 = cbuf + (b * N_ + 2 * node + 1) * H_ + ct * 128;
            const float* c2 = c1 + H_;
            float* dst = cagg + bj * H_ + ct * 128;
#pragma unroll
            for (int g = 0; g < 2; ++g) {
                const int off = (g ? 64 : 0) + (tc << 2);
                const int jb = g * 4;
                float4 cc1 = *(const float4*)(c1 + off);
                float4 cc2 = *(const float4*)(c2 + off);
                float4 bbv = *(const float4*)(Ufb + ct * 128 + off);
                float4 res;
                res.x = sigf(acc[2*p][jb+0] + bbv.x) * cc1.x + sigf(acc[2*p+1][jb+0] + bbv.x) * cc2.x;
                res.y = sigf(acc[2*p][jb+1] + bbv.y) * cc1.y + sigf(acc[2*p+1][jb+1] + bbv.y) * cc2.y;
                res.z = sigf(acc[2*p][jb+2] + bbv.z) * cc1.z + sigf(acc[2*p+1][jb+2] + bbv.z) * cc2.z;
                res.w = sigf(acc[2*p][jb+3] + bbv.w) * cc1.w + sigf(acc[2*p+1][jb+3] + bbv.w) * cc2.w;
                *(float4*)(dst + off) = res;
            }
        }
    }
}

// ---- iou small body (64x64 tile, 4x4 micro); LDS [8][72] x2 ----
__device__ __forceinline__ void iou_small_body(
    const int* __restrict__ node_feat, const int* __restrict__ mask,
    const float* __restrict__ emb, const float* __restrict__ Wiou,
    const float* __restrict__ Uiou, const float* __restrict__ hbuf,
    float* __restrict__ iou_out, int first, int n, int nshift,
    int rt, int ct, float (*As)[72], float (*Bs)[72])
{
    const int rows = B_ * n;
    const int tid = threadIdx.x;
    const int tr = tid >> 4, tc = tid & 15;

    float acc[4][4];
#pragma unroll
    for (int i = 0; i < 4; ++i)
#pragma unroll
        for (int j = 0; j < 4; ++j) acc[i][j] = 0.0f;

    const int srow = tid & 63, skq = tid >> 6;
    const int grow = rt * 64 + srow;
    const bool rvalid = grow < rows;
    int tok = 0; float mval = 0.f; int hoff1 = 0, hoff2 = 0;
    if (rvalid) {
        const int b = grow >> nshift, j = grow & (n - 1);
        const int node = first + j;
        tok  = node_feat[b * N_ + node];
        mval = (float)mask[b * N_ + node];
        hoff1 = (b * N_ + 2 * node + 1) * H_;
        hoff2 = hoff1 + H_;
    }
    const int gcol = ct * 64 + srow;

    for (int kt = 0; kt < 96; ++kt) {
        const int k0 = kt << 3;
        {
            const int kg = k0 + (skq << 1);
            float2 v = make_float2(0.f, 0.f);
            if (rvalid) {
                if (kg < E_) {
                    float2 e = *(const float2*)(emb + tok * E_ + kg);
                    v.x = e.x * mval; v.y = e.y * mval;
                } else {
                    const int kk = kg - E_;
                    float2 h1 = *(const float2*)(hbuf + hoff1 + kk);
                    float2 h2 = *(const float2*)(hbuf + hoff2 + kk);
                    v.x = h1.x + h2.x; v.y = h1.y + h2.y;
                }
            }
            As[(skq << 1) + 0][srow] = v.x;
            As[(skq << 1) + 1][srow] = v.y;
        }
        {
            const int kg = k0 + (skq << 1);
            const float* s0 = (kg < E_) ? (Wiou + (size_t)kg * 1536 + gcol)
                                        : (Uiou + (size_t)(kg - E_) * 1536 + gcol);
            const float* s1 = ((kg + 1) < E_) ? (Wiou + (size_t)(kg + 1) * 1536 + gcol)
                                              : (Uiou + (size_t)(kg + 1 - E_) * 1536 + gcol);
            Bs[(skq << 1) + 0][srow] = *s0;
            Bs[(skq << 1) + 1][srow] = *s1;
        }
        __syncthreads();
#pragma unroll
        for (int kk = 0; kk < 8; ++kk) {
            float a[4], bb[4];
            *(float4*)&a[0]  = *(const float4*)&As[kk][tr << 2];
            *(float4*)&bb[0] = *(const float4*)&Bs[kk][tc << 2];
#pragma unroll
            for (int i = 0; i < 4; ++i)
#pragma unroll
                for (int j = 0; j < 4; ++j)
                    acc[i][j] = fmaf(a[i], bb[j], acc[i][j]);
        }
        __syncthreads();
    }
#pragma unroll
    for (int i = 0; i < 4; ++i) {
        const int r = rt * 64 + (tr << 2) + i;
        if (r < rows)
            *(float4*)(iou_out + (size_t)r * 1536 + ct * 64 + (tc << 2)) =
                make_float4(acc[i][0], acc[i][1], acc[i][2], acc[i][3]);
    }
}

// ---- fagg small body (64x64 tile, fused epilogue); LDS [8][72] x2 ----
__device__ __forceinline__ void fagg_small_body(
    const float* __restrict__ hbuf, const float* __restrict__ cbuf,
    const float* __restrict__ Ufw, const float* __restrict__ Ufb,
    float* __restrict__ cagg, int first, int n, int nshift,
    int rt, int ct, float (*As)[72], float (*Bs)[72])
{
    const int rows = 64 * n;
    const int tid = threadIdx.x;
    const int tr = tid >> 4, tc = tid & 15;

    float acc[4][4];
#pragma unroll
    for (int i = 0; i < 4; ++i)
#pragma unroll
        for (int j = 0; j < 4; ++j) acc[i][j] = 0.0f;

    const int srow = tid & 63, skq = tid >> 6;
    const int grow = rt * 64 + srow;
    const bool rvalid = grow < rows;
    int hoff = 0;
    if (rvalid) {
        const int bj = grow >> 1, s = grow & 1;
        const int b = bj >> nshift, j = bj & (n - 1);
        const int node = first + j;
        hoff = (b * N_ + 2 * node + 1 + s) * H_;
    }
    const int gcol = ct * 64 + srow;

    for (int kt = 0; kt < 64; ++kt) {
        const int k0 = kt << 3;
        {
            const int kg = k0 + (skq << 1);
            float2 v = make_float2(0.f, 0.f);
            if (rvalid) v = *(const float2*)(hbuf + hoff + kg);
            As[(skq << 1) + 0][srow] = v.x;
            As[(skq << 1) + 1][srow] = v.y;
        }
        {
            const int kg = k0 + (skq << 1);
            Bs[(skq << 1) + 0][srow] = Ufw[(size_t)kg * H_ + gcol];
            Bs[(skq << 1) + 1][srow] = Ufw[(size_t)(kg + 1) * H_ + gcol];
        }
        __syncthreads();
#pragma unroll
        for (int kk = 0; kk < 8; ++kk) {
            float a[4], bb[4];
            *(float4*)&a[0]  = *(const float4*)&As[kk][tr << 2];
            *(float4*)&bb[0] = *(const float4*)&Bs[kk][tc << 2];
#pragma unroll
            for (int i = 0; i < 4; ++i)
#pragma unroll
                for (int j = 0; j < 4; ++j)
                    acc[i][j] = fmaf(a[i], bb[j], acc[i][j]);
        }
        __syncthreads();
    }
#pragma unroll
    for (int p = 0; p < 2; ++p) {
        const int r0 = rt * 64 + (tr << 2) + 2 * p;
        if (r0 < rows) {
            const int bj = r0 >> 1;
            const int b = bj >> nshift, j = bj & (n - 1);
            const int node = first + j;
            const float* c1 = cbuf + (b * N_ + 2 * node + 1) * H_ + ct * 64;
            const float* c2 = c1 + H_;
            float* dst = cagg + bj * H_ + ct * 64;
            const int off = tc << 2;
            float4 cc1 = *(const float4*)(c1 + off);
            float4 cc2 = *(const float4*)(c2 + off);
            float4 bbv = *(const float4*)(Ufb + ct * 64 + off);
            float4 res;
            res.x = sigf(acc[2*p][0] + bbv.x) * cc1.x + sigf(acc[2*p+1][0] + bbv.x) * cc2.x;
            res.y = sigf(acc[2*p][1] + bbv.y) * cc1.y + sigf(acc[2*p+1][1] + bbv.y) * cc2.y;
            res.z = sigf(acc[2*p][2] + bbv.z) * cc1.z + sigf(acc[2*p+1][2] + bbv.z) * cc2.z;
            res.w = sigf(acc[2*p][3] + bbv.w) * cc1.w + sigf(acc[2*p+1][3] + bbv.w) * cc2.w;
            *(float4*)(dst + off) = res;
        }
    }
}

// ===========================================================================
// Thin globals
// ===========================================================================

// leaves only (iou, K=256)
template<bool LEAF>
__global__ void __launch_bounds__(256)
iou_gemm_k(const int* __restrict__ node_feat, const int* __restrict__ mask,
           const float* __restrict__ emb, const float* __restrict__ Wiou,
           const float* __restrict__ Uiou, const float* __restrict__ hbuf,
           float* __restrict__ iou_out, int first, int n, int nshift)
{
    __shared__ __align__(16) float As[8][136];
    __shared__ __align__(16) float Bs[8][136];
    iou_body<LEAF>(node_feat, mask, emb, Wiou, Uiou, hbuf, iou_out,
                   first, n, nshift, blockIdx.x, blockIdx.y, As, Bs);
}

// merged fagg+iou, big internal levels (n>=128)
__global__ void __launch_bounds__(256)
tree_big_k(const int* __restrict__ node_feat, const int* __restrict__ mask,
           const float* __restrict__ emb, const float* __restrict__ Wiou,
           const float* __restrict__ Uiou, const float* __restrict__ hbuf,
           const float* __restrict__ cbuf, const float* __restrict__ Ufw,
           const float* __restrict__ Ufb, float* __restrict__ cagg,
           float* __restrict__ iou_out, int first, int n, int nshift)
{
    __shared__ __align__(16) float As[8][136];
    __shared__ __align__(16) float Bs[8][136];
    const int nf_rt = n >> 1;            // fagg row-tiles
    const int Nf    = nf_rt << 2;        // fagg blocks (x4 col tiles)
    const int bid   = blockIdx.x;
    if (bid < Nf) {
        fagg_body(hbuf, cbuf, Ufw, Ufb, cagg, first, n, nshift,
                  bid % nf_rt, bid / nf_rt, As, Bs);
    } else {
        const int b2 = bid - Nf;
        const int ni_rt = n >> 2;        // iou row-tiles
        iou_body<false>(node_feat, mask, emb, Wiou, Uiou, hbuf, iou_out,
                        first, n, nshift, b2 % ni_rt, b2 / ni_rt, As, Bs);
    }
}

// merged fagg+iou, small internal levels (n<=64)
__global__ void __launch_bounds__(256)
tree_small_k(const int* __restrict__ node_feat, const int* __restrict__ mask,
             const float* __restrict__ emb, const float* __restrict__ Wiou,
             const float* __restrict__ Uiou, const float* __restrict__ hbuf,
             const float* __restrict__ cbuf, const float* __restrict__ Ufw,
             const float* __restrict__ Ufb, float* __restrict__ cagg,
             float* __restrict__ iou_out, int first, int n, int nshift)
{
    __shared__ __align__(16) float As[8][72];
    __shared__ __align__(16) float Bs[8][72];
    const int nf_rt = n;                 // fagg row-tiles (64 rows each)
    const int Nf    = nf_rt << 3;        // x8 col tiles
    const int bid   = blockIdx.x;
    if (bid < Nf) {
        fagg_small_body(hbuf, cbuf, Ufw, Ufb, cagg, first, n, nshift,
                        bid % nf_rt, bid / nf_rt, As, Bs);
    } else {
        const int b2 = bid - Nf;
        const int ni_rt = (n >= 2) ? (n >> 1) : 1;
        iou_small_body(node_feat, mask, emb, Wiou, Uiou, hbuf, iou_out,
                       first, n, nshift, b2 % ni_rt, b2 / ni_rt, As, Bs);
    }
}

// ---------------------------------------------------------------------------
// apply_node (all levels)
// ---------------------------------------------------------------------------
template<bool LEAF>
__global__ void apply_node_k(const float* __restrict__ iou,
                             const float* __restrict__ b_iou,
                             const float* __restrict__ cagg,
                             float* __restrict__ hbuf, float* __restrict__ cbuf,
                             int first, int n, int nshift)
{
    const int gid = blockIdx.x * 256 + threadIdx.x;
    if (gid >= B_ * n * 128) return;
    const int r = gid >> 7, col = (gid & 127) << 2;
    const float* row = iou + (size_t)r * 1536;
    float4 iv = *(const float4*)(row + col);
    float4 ov = *(const float4*)(row + 512 + col);
    float4 uv = *(const float4*)(row + 1024 + col);
    float4 bi = *(const float4*)(b_iou + col);
    float4 bo = *(const float4*)(b_iou + 512 + col);
    float4 bu = *(const float4*)(b_iou + 1024 + col);
    float4 ca = make_float4(0.f, 0.f, 0.f, 0.f);
    if (!LEAF) ca = *(const float4*)(cagg + r * H_ + col);
    float4 cn, hn;
    cn.x = sigf(iv.x + bi.x) * tanhf(uv.x + bu.x) + ca.x;
    cn.y = sigf(iv.y + bi.y) * tanhf(uv.y + bu.y) + ca.y;
    cn.z = sigf(iv.z + bi.z) * tanhf(uv.z + bu.z) + ca.z;
    cn.w = sigf(iv.w + bi.w) * tanhf(uv.w + bu.w) + ca.w;
    hn.x = sigf(ov.x + bo.x) * tanhf(cn.x);
    hn.y = sigf(ov.y + bo.y) * tanhf(cn.y);
    hn.z = sigf(ov.z + bo.z) * tanhf(cn.z);
    hn.w = sigf(ov.w + bo.w) * tanhf(cn.w);
    const int b = r >> nshift, j = r & (n - 1);
    const int node = first + j;
    const size_t o = (size_t)(b * N_ + node) * H_ + col;
    *(float4*)(cbuf + o) = cn;
    *(float4*)(hbuf + o) = hn;
}

// ---------------------------------------------------------------------------
// two-stage mean over nodes
// ---------------------------------------------------------------------------
__global__ void mean_part_k(const float* __restrict__ hbuf, float* __restrict__ mpart)
{
    const int bid = blockIdx.x;               // 256 = 32 b x 8 chunks
    const int b = bid >> 3, chunk = bid & 7;
    const int tid = threadIdx.x;
    const int n0 = chunk * 128;
    const int n1 = (n0 + 128 < N_) ? (n0 + 128) : N_;
    float s0 = 0.f, s1 = 0.f;
    for (int nn = n0; nn < n1; ++nn) {
        const float* p = hbuf + (size_t)(b * N_ + nn) * H_;
        s0 += p[tid];
        s1 += p[tid + 256];
    }
    mpart[(bid << 9) + tid]       = s0;
    mpart[(bid << 9) + tid + 256] = s1;
}

__global__ void mean_fin_k(const float* __restrict__ mpart, float* __restrict__ mf)
{
    const int gid = blockIdx.x * 256 + threadIdx.x;   // 16384
    const int b = gid >> 9, k = gid & 511;
    float s = 0.f;
#pragma unroll
    for (int c = 0; c < 8; ++c) s += mpart[(((b << 3) + c) << 9) + k];
    mf[gid] = s * (1.0f / 1023.0f);
}

__global__ void hidcel_k(const float* __restrict__ mf,
                         const float* __restrict__ hw, const float* __restrict__ hb,
                         const float* __restrict__ cw, const float* __restrict__ cb,
                         float* __restrict__ hs0, float* __restrict__ cs)
{
    const int gid = blockIdx.x * 256 + threadIdx.x;   // 32768
    const int which = gid >> 14;
    const int b = (gid >> 9) & 31, l = gid & 511;
    const float* W = which ? cw : hw;
    float acc = which ? cb[l] : hb[l];
#pragma unroll 8
    for (int k = 0; k < H_; ++k) acc = fmaf(mf[b * H_ + k], W[k * H_ + l], acc);
    if (which) cs[b * H_ + l] = acc; else hs0[b * H_ + l] = acc;
}

// ---------------------------------------------------------------------------
// gate-weight transpose: Wt[g][k] (g in [0,2048), k in [0,768))
// ---------------------------------------------------------------------------
__global__ void __launch_bounds__(256)
wtrans_k(const float* __restrict__ W_ih, const float* __restrict__ W_hh,
         float* __restrict__ Wt)
{
    __shared__ float t[64][33];
    const int k0 = blockIdx.x * 32;   // 24 k-tiles
    const int g0 = blockIdx.y * 64;   // 32 g-tiles
    const int tid = threadIdx.x;
    for (int idx = tid; idx < 2048; idx += 256) {
        const int kk = idx >> 6, gg = idx & 63;
        const int k = k0 + kk;
        t[gg][kk] = (k < E_) ? W_ih[(size_t)k * 2048 + g0 + gg]
                             : W_hh[(size_t)(k - E_) * 2048 + g0 + gg];
    }
    __syncthreads();
    for (int idx = tid; idx < 2048; idx += 256) {
        const int gg = idx >> 5, kk = idx & 31;
        Wt[(size_t)(g0 + gg) * 768 + k0 + kk] = t[gg][kk];
    }
}

// ---------------------------------------------------------------------------
// decoder LSTM step v6 (R11 proven): transposed Wt, float4 k-sweeps.
// ---------------------------------------------------------------------------
__global__ void __launch_bounds__(256)
lstm_step_k(const float* __restrict__ emb, const float* __restrict__ Wt,
            const float* __restrict__ b_ih, const float* __restrict__ b_hh,
            const float* __restrict__ pval, const int* __restrict__ pidx,
            const float* __restrict__ hs_in, float* __restrict__ hs_out,
            float* __restrict__ cs, int t)
{
    __shared__ __align__(16) float xh[8][776];       // 24.8 KB
    __shared__ __align__(16) float part[4][8][8][4]; // 4 KB
    __shared__ float rv[256];
    __shared__ int   ri[256];
    __shared__ int   tokS[8];
    const int tid = threadIdx.x;
    const int bg  = blockIdx.y;          // b-group (8 batches)

    if (t == 1) {
        if (tid < 8) tokS[tid] = 0;
    } else {
        const int bs = tid >> 5, th = tid & 31;     // 8 b x 32 scanners
        const int b = bg * 8 + bs;
        float bv = -INFINITY; int bi = 0x7fffffff;
        for (int p = th; p < NBL; p += 32) {
            const float v = pval[b * NBL + p];
            const int  ix = pidx[b * NBL + p];
            if (v > bv || (v == bv && ix < bi)) { bv = v; bi = ix; }
        }
        rv[tid] = bv; ri[tid] = bi;
        __syncthreads();
        if (tid < 8) {
            float Bv = -INFINITY; int Bi = 0x7fffffff;
#pragma unroll
            for (int c = 0; c < 32; ++c) {
                const float v = rv[tid * 32 + c];
                const int  ix = ri[tid * 32 + c];
                if (v > Bv || (v == Bv && ix < Bi)) { Bv = v; Bi = ix; }
            }
            tokS[tid] = Bi;
        }
    }
    __syncthreads();

    for (int idx = tid; idx < 8 * E_; idx += 256) {
        const int b = idx >> 8, k = idx & 255;
        xh[b][k] = emb[(size_t)tokS[b] * E_ + k];
    }
    for (int idx = tid; idx < 8 * H_; idx += 256) {
        const int b = idx >> 9, k = idx & 511;
        xh[b][E_ + k] = hs_in[(size_t)(bg * 8 + b) * H_ + k];
    }
    __syncthreads();

    const int ks = tid >> 6;
    const int lane = tid & 63;
    const int bi = lane >> 3, li = lane & 7;
    const int l = blockIdx.x * 8 + li;
    float ai = 0.f, af = 0.f, ag = 0.f, ao = 0.f;
    const int k0 = ks * 192;
    const float* wi = Wt + (size_t)(l)        * 768 + k0;
    const float* wf = Wt + (size_t)(512 + l)  * 768 + k0;
    const float* wg = Wt + (size_t)(1024 + l) * 768 + k0;
    const float* wo = Wt + (size_t)(1536 + l) * 768 + k0;
    const float* xp = &xh[bi][k0];
#pragma unroll 4
    for (int kk = 0; kk < 192; kk += 4) {
        const float4 xv = *(const float4*)(xp + kk);
        const float4 w0 = *(const float4*)(wi + kk);
        const float4 w1 = *(const float4*)(wf + kk);
        const float4 w2 = *(const float4*)(wg + kk);
        const float4 w3 = *(const float4*)(wo + kk);
        ai = fmaf(xv.x, w0.x, ai); ai = fmaf(xv.y, w0.y, ai);
        ai = fmaf(xv.z, w0.z, ai); ai = fmaf(xv.w, w0.w, ai);
        af = fmaf(xv.x, w1.x, af); af = fmaf(xv.y, w1.y, af);
        af = fmaf(xv.z, w1.z, af); af = fmaf(xv.w, w1.w, af);
        ag = fmaf(xv.x, w2.x, ag); ag = fmaf(xv.y, w2.y, ag);
        ag = fmaf(xv.z, w2.z, ag); ag = fmaf(xv.w, w2.w, ag);
        ao = fmaf(xv.x, w3.x, ao); ao = fmaf(xv.y, w3.y, ao);
        ao = fmaf(xv.z, w3.z, ao); ao = fmaf(xv.w, w3.w, ao);
    }
    part[ks][bi][li][0] = ai;
    part[ks][bi][li][1] = af;
    part[ks][bi][li][2] = ag;
    part[ks][bi][li][3] = ao;
    __syncthreads();

    if (tid < 64) {
        const int b2 = tid >> 3, l2i = tid & 7;
        const int l2 = blockIdx.x * 8 + l2i;
        const int b = bg * 8 + b2;
        float s0 = 0.f, s1 = 0.f, s2 = 0.f, s3 = 0.f;
#pragma unroll
        for (int q = 0; q < 4; ++q) {
            s0 += part[q][b2][l2i][0];
            s1 += part[q][b2][l2i][1];
            s2 += part[q][b2][l2i][2];
            s3 += part[q][b2][l2i][3];
        }
        const float gi = s0 + b_ih[l2]        + b_hh[l2];
        const float gf = s1 + b_ih[512 + l2]  + b_hh[512 + l2];
        const float gg = s2 + b_ih[1024 + l2] + b_hh[1024 + l2];
        const float go = s3 + b_ih[1536 + l2] + b_hh[1536 + l2];
        const float co = cs[b * H_ + l2];
        const float cn = sigf(gf) * co + sigf(gi) * tanhf(gg);
        cs[b * H_ + l2] = cn;
        hs_out[b * H_ + l2] = sigf(go) * tanhf(cn);
    }
}

// ---------------------------------------------------------------------------
// logits partial: grid (250 col-tiles, 2 k-halves). [R5 proven]
// ---------------------------------------------------------------------------
__global__ void __launch_bounds__(256)
logits_part_k(const float* __restrict__ fc_w, const float* __restrict__ hs,
              float* __restrict__ partial)
{
    __shared__ __align__(16) float sm[256 * 36];   // 36,864 B
    const int tid = threadIdx.x;
    const int blk = blockIdx.x;       // col tile (128 cols)
    const int kh  = blockIdx.y;       // k half (256 rows)

    for (int idx = tid; idx < B_ * 256; idx += 256) {
        const int b = idx & 31, k = idx >> 5;
        sm[k * 36 + b] = hs[b * H_ + kh * 256 + k];
    }
    __syncthreads();

    const int w8   = (tid >> 6) << 3;       // wave's b-chunk: 0,8,16,24
    const int lane = tid & 63;
    const int col  = (blk << 7) + (lane << 1);

    float acc[8][2];
#pragma unroll
    for (int i = 0; i < 8; ++i) { acc[i][0] = 0.f; acc[i][1] = 0.f; }

    const float* wp = fc_w + (size_t)(kh * 256) * V_ + col;
    const float* hp = sm + w8;
    float2 wreg[8];
#pragma unroll
    for (int j = 0; j < 8; ++j) wreg[j] = *(const float2*)(wp + (size_t)j * V_);
    for (int kb = 0; kb < 32; ++kb) {
        float2 wnxt[8];
        if (kb < 31) {
            const float* wq = wp + (size_t)((kb + 1) << 3) * V_;
#pragma unroll
            for (int j = 0; j < 8; ++j) wnxt[j] = *(const float2*)(wq + (size_t)j * V_);
        }
#pragma unroll
        for (int j = 0; j < 8; ++j) {
            const float* hq = hp + ((kb << 3) + j) * 36;   // wave-uniform LDS broadcast
            float hv[8];
            *(float4*)&hv[0] = *(const float4*)(hq);
            *(float4*)&hv[4] = *(const float4*)(hq + 4);
#pragma unroll
            for (int i = 0; i < 8; ++i) {
                acc[i][0] = fmaf(hv[i], wreg[j].x, acc[i][0]);
                acc[i][1] = fmaf(hv[i], wreg[j].y, acc[i][1]);
            }
        }
        if (kb < 31) {
#pragma unroll
            for (int j = 0; j < 8; ++j) wreg[j] = wnxt[j];
        }
    }
#pragma unroll
    for (int i = 0; i < 8; ++i) {
        float* dst = partial + (size_t)(kh * B_ + w8 + i) * V_ + col;
        *(float2*)dst = make_float2(acc[i][0], acc[i][1]);
    }
}

// ---------------------------------------------------------------------------
// logits finalize: 250 blocks. sum 2 halves + bias -> out (NT stores),
// block argmax.
// ---------------------------------------------------------------------------
__global__ void __launch_bounds__(256)
logits_fin_k(const float* __restrict__ partial, const float* __restrict__ fc_b,
             float* __restrict__ out_t, float* __restrict__ pval,
             int* __restrict__ pidx)
{
    __shared__ float rv[256];
    __shared__ int   ri[256];
    const int tid = threadIdx.x, blk = blockIdx.x;
    const int b = tid >> 3, cg = (tid & 7) << 4;
    const int colbase = (blk << 7) + cg;

    const float* p0 = partial + (size_t)b * V_ + colbase;
    const float* p1 = partial + (size_t)(B_ + b) * V_ + colbase;
    const float* bp = fc_b + colbase;
    float* op = out_t + (size_t)b * V_ + colbase;

    float bv = -INFINITY; int bi = 0;
#pragma unroll
    for (int q = 0; q < 4; ++q) {
        float4 a = *(const float4*)(p0 + (q << 2));
        float4 c = *(const float4*)(p1 + (q << 2));
        float4 d = *(const float4*)(bp + (q << 2));
        float4 v;
        v.x = a.x + c.x + d.x; v.y = a.y + c.y + d.y;
        v.z = a.z + c.z + d.z; v.w = a.w + c.w + d.w;
        nt_store4(op + (q << 2), v);   // keep fc_w L3-resident
        const int c0 = cg + (q << 2);
        if (v.x > bv) { bv = v.x; bi = c0 + 0; }
        if (v.y > bv) { bv = v.y; bi = c0 + 1; }
        if (v.z > bv) { bv = v.z; bi = c0 + 2; }
        if (v.w > bv) { bv = v.w; bi = c0 + 3; }
    }
    rv[tid] = bv; ri[tid] = bi;
    __syncthreads();
    if (tid < B_) {
        float Bv = -INFINITY; int Bi = 0;
#pragma unroll
        for (int q = 0; q < 8; ++q) {
            const float v = rv[(tid << 3) + q];     // ascending col order
            if (v > Bv) { Bv = v; Bi = ri[(tid << 3) + q]; }
        }
        pval[tid * NBL + blk] = Bv;
        pidx[tid * NBL + blk] = (blk << 7) + Bi;
    }
}

// ---------------------------------------------------------------------------
extern "C" void kernel_launch(void* const* d_in, const int* in_sizes, int n_in,
                              void* d_out, int out_size, void* d_ws, size_t ws_size,
                              hipStream_t stream)
{
    (void)in_sizes; (void)n_in; (void)out_size; (void)ws_size;
    const int*   node_feat = (const int*)  d_in[0];
    const int*   mask      = (const int*)  d_in[1];
    const float* emb       = (const float*)d_in[2];
    const float* W_iou     = (const float*)d_in[3];
    const float* U_iou     = (const float*)d_in[4];
    const float* b_iou     = (const float*)d_in[5];
    const float* U_f_w     = (const float*)d_in[6];
    const float* U_f_b     = (const float*)d_in[7];
    const float* hid_fc_w  = (const float*)d_in[8];
    const float* hid_fc_b  = (const float*)d_in[9];
    const float* cell_fc_w = (const float*)d_in[10];
    const float* cell_fc_b = (const float*)d_in[11];
    const float* W_ih      = (const float*)d_in[12];
    const float* W_hh      = (const float*)d_in[13];
    const float* b_ih      = (const float*)d_in[14];
    const float* b_hh      = (const float*)d_in[15];
    const float* fc_w      = (const float*)d_in[16];
    const float* fc_b      = (const float*)d_in[17];
    float* out = (float*)d_out;

    float* ws      = (float*)d_ws;
    float* iou_buf = ws;                      // 12,582,912 (8192 x 1536)
    float* cagg    = ws + 12582912;           //  4,194,304
    float* hbuf    = ws + 16777216;           // 16,760,832
    float* cbuf    = ws + 33538048;           // 16,760,832
    float* mf      = ws + 50298880;           //     16,384
    float* hsb     = ws + 50315264;           //     32,768 (ping-pong)
    float* csb     = ws + 50348032;           //     16,384
    float* pval    = ws + 50364416;           //      8,000 (32 x 250)
    int*   pidx    = (int*)(ws + 50372416);   //      8,000
    // after the tree, iou_buf is dead -> reuse
    float* mpart   = iou_buf;                 //    131,072 floats
    float* partial = iou_buf + 262144;        //  2,048,000 floats (2 x 32 x V)
    float* Wt      = iou_buf + 2359296;       //  1,572,864 floats (2048 x 768)

    // ---- tree: leaves (2 chunks of 256 nodes) ----
    for (int chunk = 0; chunk < 2; ++chunk) {
        const int first = 511 + 256 * chunk;
        dim3 g(64, 12);
        iou_gemm_k<true><<<g, 256, 0, stream>>>(node_feat, mask, emb, W_iou, U_iou,
                                                hbuf, iou_buf, first, 256, 8);
        apply_node_k<true><<<4096, 256, 0, stream>>>(iou_buf, b_iou, cagg,
                                                     hbuf, cbuf, first, 256, 8);
    }
    // ---- tree: internal levels (merged fagg+iou per level) ----
    for (int d = 8; d >= 0; --d) {
        const int n = 1 << d, first = n - 1;
        if (n >= 128) {
            const int nb = (n >> 1) * 4 + (n >> 2) * 12;
            tree_big_k<<<nb, 256, 0, stream>>>(node_feat, mask, emb, W_iou, U_iou,
                                               hbuf, cbuf, U_f_w, U_f_b, cagg,
                                               iou_buf, first, n, d);
        } else {
            const int ni_rt = (n >= 2) ? (n >> 1) : 1;
            const int nb = n * 8 + ni_rt * 24;
            tree_small_k<<<nb, 256, 0, stream>>>(node_feat, mask, emb, W_iou, U_iou,
                                                 hbuf, cbuf, U_f_w, U_f_b, cagg,
                                                 iou_buf, first, n, d);
        }
        apply_node_k<false><<<16 * n, 256, 0, stream>>>(iou_buf, b_iou, cagg,
                                                        hbuf, cbuf, first, n, d);
    }
    // ---- pool + init + gate-weight transpose (iou_buf dead from here) ----
    mean_part_k<<<256, 256, 0, stream>>>(hbuf, mpart);
    mean_fin_k<<<64, 256, 0, stream>>>(mpart, mf);
    hidcel_k<<<128, 256, 0, stream>>>(mf, hid_fc_w, hid_fc_b, cell_fc_w, cell_fc_b, hsb, csb);
    dim3 gw(24, 32);
    wtrans_k<<<gw, 256, 0, stream>>>(W_ih, W_hh, Wt);
    // ---- out[0] = 0 ----
    hipMemsetAsync(d_out, 0, (size_t)B_ * V_ * sizeof(float), stream);
    // ---- decoder: 3 kernels per step ----
    for (int t = 1; t < T_; ++t) {
        const float* hs_in  = hsb + ((t - 1) & 1) * (B_ * H_);
        float*       hs_out = hsb + (t & 1) * (B_ * H_);
        dim3 gl(64, 4);
        lstm_step_k<<<gl, 256, 0, stream>>>(emb, Wt, b_ih, b_hh,
                                            pval, pidx, hs_in, hs_out, csb, t);
        dim3 gp(NBL, 2);
        logits_part_k<<<gp, 256, 0, stream>>>(fc_w, hs_out, partial);
        logits_fin_k<<<NBL, 256, 0, stream>>>(partial, fc_b,
                                              out + (size_t)t * B_ * V_, pval, pidx);
    }
}

// Round 15
// 5848.450 us; speedup vs baseline: 1.0768x; 1.0107x over previous
//
#include <hip/hip_runtime.h>
#include <math.h>

#define B_ 32
#define N_ 1023
#define E_ 256
#define H_ 512
#define V_ 32000
#define T_ 64
#define NBL 250   // logits col-tiles (128 cols each)

__device__ __forceinline__ float sigf(float x) { return 1.0f / (1.0f + expf(-x)); }

__device__ __forceinline__ void nt_store4(float* p, float4 v)
{
    __builtin_nontemporal_store(v.x, p + 0);
    __builtin_nontemporal_store(v.y, p + 1);
    __builtin_nontemporal_store(v.z, p + 2);
    __builtin_nontemporal_store(v.w, p + 3);
}

// ---------------------------------------------------------------------------
// Tree iou GEMM (large levels + leaves): 128x128 tile, 8x8 micro. [R11 proven]
// ---------------------------------------------------------------------------
template<bool LEAF>
__global__ void __launch_bounds__(256)
iou_gemm_k(const int* __restrict__ node_feat, const int* __restrict__ mask,
           const float* __restrict__ emb, const float* __restrict__ Wiou,
           const float* __restrict__ Uiou, const float* __restrict__ hbuf,
           float* __restrict__ iou_out, int first, int n, int nshift)
{
    const int rows = B_ * n;
    const int K = LEAF ? E_ : (E_ + H_);
    const int rt = blockIdx.x, ct = blockIdx.y;
    const int tid = threadIdx.x;
    const int tr = tid >> 4, tc = tid & 15;

    __shared__ __align__(16) float As[8][136];
    __shared__ __align__(16) float Bs[8][136];

    float acc[8][8];
#pragma unroll
    for (int i = 0; i < 8; ++i)
#pragma unroll
        for (int j = 0; j < 8; ++j) acc[i][j] = 0.0f;

    const int lrow = tid >> 1;
    const int lkq  = (tid & 1) << 2;
    const int grow = rt * 128 + lrow;
    const bool rvalid = grow < rows;
    int tok = 0; float mval = 0.0f; int hoff1 = 0, hoff2 = 0;
    if (rvalid) {
        const int b = grow >> nshift, j = grow & (n - 1);
        const int node = first + j;
        tok  = node_feat[b * N_ + node];
        mval = (float)mask[b * N_ + node];
        if (!LEAF) {
            hoff1 = (b * N_ + 2 * node + 1) * H_;
            hoff2 = hoff1 + H_;
        }
    }
    const int bk   = tid >> 5;
    const int bcol = (tid & 31) << 2;
    const int gcol = ct * 128 + bcol;

    const int nkt = K >> 3;
    for (int kt = 0; kt < nkt; ++kt) {
        const int k0 = kt << 3;
        {
            const int kg = k0 + lkq;
            float4 v = make_float4(0.f, 0.f, 0.f, 0.f);
            if (rvalid) {
                if (LEAF || kg < E_) {
                    float4 e = *(const float4*)(emb + tok * E_ + kg);
                    v.x = e.x * mval; v.y = e.y * mval; v.z = e.z * mval; v.w = e.w * mval;
                } else {
                    const int kk = kg - E_;
                    float4 h1 = *(const float4*)(hbuf + hoff1 + kk);
                    float4 h2 = *(const float4*)(hbuf + hoff2 + kk);
                    v.x = h1.x + h2.x; v.y = h1.y + h2.y;
                    v.z = h1.z + h2.z; v.w = h1.w + h2.w;
                }
            }
            As[lkq + 0][lrow] = v.x;
            As[lkq + 1][lrow] = v.y;
            As[lkq + 2][lrow] = v.z;
            As[lkq + 3][lrow] = v.w;
        }
        {
            const int kg = k0 + bk;
            const float* src = (LEAF || kg < E_) ? (Wiou + kg * 1536 + gcol)
                                                 : (Uiou + (kg - E_) * 1536 + gcol);
            *(float4*)&Bs[bk][bcol] = *(const float4*)src;
        }
        __syncthreads();
#pragma unroll
        for (int kk = 0; kk < 8; ++kk) {
            float a[8], bb[8];
            *(float4*)&a[0]  = *(const float4*)&As[kk][tr << 3];
            *(float4*)&a[4]  = *(const float4*)&As[kk][(tr << 3) + 4];
            *(float4*)&bb[0] = *(const float4*)&Bs[kk][tc << 2];
            *(float4*)&bb[4] = *(const float4*)&Bs[kk][(tc << 2) + 64];
#pragma unroll
            for (int i = 0; i < 8; ++i)
#pragma unroll
                for (int j = 0; j < 8; ++j)
                    acc[i][j] = fmaf(a[i], bb[j], acc[i][j]);
        }
        __syncthreads();
    }
#pragma unroll
    for (int i = 0; i < 8; ++i) {
        const int r = rt * 128 + (tr << 3) + i;
        if (r < rows) {
            float* dst = iou_out + (size_t)r * 1536 + ct * 128;
            *(float4*)(dst + (tc << 2))      = make_float4(acc[i][0], acc[i][1], acc[i][2], acc[i][3]);
            *(float4*)(dst + 64 + (tc << 2)) = make_float4(acc[i][4], acc[i][5], acc[i][6], acc[i][7]);
        }
    }
}

// ---------------------------------------------------------------------------
// f-gate GEMM (large levels): 128x128 tile with fused c_agg epilogue. [R11]
// ---------------------------------------------------------------------------
__global__ void __launch_bounds__(256)
fagg_gemm_k(const float* __restrict__ hbuf, const float* __restrict__ cbuf,
            const float* __restrict__ Ufw, const float* __restrict__ Ufb,
            float* __restrict__ cagg, int first, int n, int nshift)
{
    const int rows = 64 * n;
    const int rt = blockIdx.x, ct = blockIdx.y;
    const int tid = threadIdx.x;
    const int tr = tid >> 4, tc = tid & 15;

    __shared__ __align__(16) float As[8][136];
    __shared__ __align__(16) float Bs[8][136];

    float acc[8][8];
#pragma unroll
    for (int i = 0; i < 8; ++i)
#pragma unroll
        for (int j = 0; j < 8; ++j) acc[i][j] = 0.0f;

    const int lrow = tid >> 1;
    const int lkq  = (tid & 1) << 2;
    const int grow = rt * 128 + lrow;
    const bool rvalid = grow < rows;
    int hoff = 0;
    if (rvalid) {
        const int bj = grow >> 1, s = grow & 1;
        const int b = bj >> nshift, j = bj & (n - 1);
        const int node = first + j;
        hoff = (b * N_ + 2 * node + 1 + s) * H_;
    }
    const int bk   = tid >> 5;
    const int bcol = (tid & 31) << 2;
    const int gcol = ct * 128 + bcol;

    for (int kt = 0; kt < 64; ++kt) {
        const int k0 = kt << 3;
        {
            const int kg = k0 + lkq;
            float4 v = make_float4(0.f, 0.f, 0.f, 0.f);
            if (rvalid) v = *(const float4*)(hbuf + hoff + kg);
            As[lkq + 0][lrow] = v.x;
            As[lkq + 1][lrow] = v.y;
            As[lkq + 2][lrow] = v.z;
            As[lkq + 3][lrow] = v.w;
        }
        {
            const int kg = k0 + bk;
            *(float4*)&Bs[bk][bcol] = *(const float4*)(Ufw + kg * H_ + gcol);
        }
        __syncthreads();
#pragma unroll
        for (int kk = 0; kk < 8; ++kk) {
            float a[8], bb[8];
            *(float4*)&a[0]  = *(const float4*)&As[kk][tr << 3];
            *(float4*)&a[4]  = *(const float4*)&As[kk][(tr << 3) + 4];
            *(float4*)&bb[0] = *(const float4*)&Bs[kk][tc << 2];
            *(float4*)&bb[4] = *(const float4*)&Bs[kk][(tc << 2) + 64];
#pragma unroll
            for (int i = 0; i < 8; ++i)
#pragma unroll
                for (int j = 0; j < 8; ++j)
                    acc[i][j] = fmaf(a[i], bb[j], acc[i][j]);
        }
        __syncthreads();
    }
#pragma unroll
    for (int p = 0; p < 4; ++p) {
        const int r0 = rt * 128 + (tr << 3) + 2 * p;
        if (r0 < rows) {
            const int bj = r0 >> 1;
            const int b = bj >> nshift, j = bj & (n - 1);
            const int node = first + j;
            const float* c1 = cbuf + (b * N_ + 2 * node + 1) * H_ + ct * 128;
            const float* c2 = c1 + H_;
            float* dst = cagg + bj * H_ + ct * 128;
#pragma unroll
            for (int g = 0; g < 2; ++g) {
                const int off = (g ? 64 : 0) + (tc << 2);
                const int jb = g * 4;
                float4 cc1 = *(const float4*)(c1 + off);
                float4 cc2 = *(const float4*)(c2 + off);
                float4 bbv = *(const float4*)(Ufb + ct * 128 + off);
                float4 res;
                res.x = sigf(acc[2*p][jb+0] + bbv.x) * cc1.x + sigf(acc[2*p+1][jb+0] + bbv.x) * cc2.x;
                res.y = sigf(acc[2*p][jb+1] + bbv.y) * cc1.y + sigf(acc[2*p+1][jb+1] + bbv.y) * cc2.y;
                res.z = sigf(acc[2*p][jb+2] + bbv.z) * cc1.z + sigf(acc[2*p+1][jb+2] + bbv.z) * cc2.z;
                res.w = sigf(acc[2*p][jb+3] + bbv.w) * cc1.w + sigf(acc[2*p+1][jb+3] + bbv.w) * cc2.w;
                *(float4*)(dst + off) = res;
            }
        }
    }
}

// ===========================================================================
// Small-level bodies (n<=64), merged into one dispatch per level [R14 proven]
// ===========================================================================

__device__ __forceinline__ void iou_small_body(
    const int* __restrict__ node_feat, const int* __restrict__ mask,
    const float* __restrict__ emb, const float* __restrict__ Wiou,
    const float* __restrict__ Uiou, const float* __restrict__ hbuf,
    float* __restrict__ iou_out, int first, int n, int nshift,
    int rt, int ct, float (*As)[72], float (*Bs)[72])
{
    const int rows = B_ * n;
    const int tid = threadIdx.x;
    const int tr = tid >> 4, tc = tid & 15;

    float acc[4][4];
#pragma unroll
    for (int i = 0; i < 4; ++i)
#pragma unroll
        for (int j = 0; j < 4; ++j) acc[i][j] = 0.0f;

    const int srow = tid & 63, skq = tid >> 6;
    const int grow = rt * 64 + srow;
    const bool rvalid = grow < rows;
    int tok = 0; float mval = 0.f; int hoff1 = 0, hoff2 = 0;
    if (rvalid) {
        const int b = grow >> nshift, j = grow & (n - 1);
        const int node = first + j;
        tok  = node_feat[b * N_ + node];
        mval = (float)mask[b * N_ + node];
        hoff1 = (b * N_ + 2 * node + 1) * H_;
        hoff2 = hoff1 + H_;
    }
    const int gcol = ct * 64 + srow;

    for (int kt = 0; kt < 96; ++kt) {
        const int k0 = kt << 3;
        {
            const int kg = k0 + (skq << 1);
            float2 v = make_float2(0.f, 0.f);
            if (rvalid) {
                if (kg < E_) {
                    float2 e = *(const float2*)(emb + tok * E_ + kg);
                    v.x = e.x * mval; v.y = e.y * mval;
                } else {
                    const int kk = kg - E_;
                    float2 h1 = *(const float2*)(hbuf + hoff1 + kk);
                    float2 h2 = *(const float2*)(hbuf + hoff2 + kk);
                    v.x = h1.x + h2.x; v.y = h1.y + h2.y;
                }
            }
            As[(skq << 1) + 0][srow] = v.x;
            As[(skq << 1) + 1][srow] = v.y;
        }
        {
            const int kg = k0 + (skq << 1);
            const float* s0 = (kg < E_) ? (Wiou + (size_t)kg * 1536 + gcol)
                                        : (Uiou + (size_t)(kg - E_) * 1536 + gcol);
            const float* s1 = ((kg + 1) < E_) ? (Wiou + (size_t)(kg + 1) * 1536 + gcol)
                                              : (Uiou + (size_t)(kg + 1 - E_) * 1536 + gcol);
            Bs[(skq << 1) + 0][srow] = *s0;
            Bs[(skq << 1) + 1][srow] = *s1;
        }
        __syncthreads();
#pragma unroll
        for (int kk = 0; kk < 8; ++kk) {
            float a[4], bb[4];
            *(float4*)&a[0]  = *(const float4*)&As[kk][tr << 2];
            *(float4*)&bb[0] = *(const float4*)&Bs[kk][tc << 2];
#pragma unroll
            for (int i = 0; i < 4; ++i)
#pragma unroll
                for (int j = 0; j < 4; ++j)
                    acc[i][j] = fmaf(a[i], bb[j], acc[i][j]);
        }
        __syncthreads();
    }
#pragma unroll
    for (int i = 0; i < 4; ++i) {
        const int r = rt * 64 + (tr << 2) + i;
        if (r < rows)
            *(float4*)(iou_out + (size_t)r * 1536 + ct * 64 + (tc << 2)) =
                make_float4(acc[i][0], acc[i][1], acc[i][2], acc[i][3]);
    }
}

__device__ __forceinline__ void fagg_small_body(
    const float* __restrict__ hbuf, const float* __restrict__ cbuf,
    const float* __restrict__ Ufw, const float* __restrict__ Ufb,
    float* __restrict__ cagg, int first, int n, int nshift,
    int rt, int ct, float (*As)[72], float (*Bs)[72])
{
    const int rows = 64 * n;
    const int tid = threadIdx.x;
    const int tr = tid >> 4, tc = tid & 15;

    float acc[4][4];
#pragma unroll
    for (int i = 0; i < 4; ++i)
#pragma unroll
        for (int j = 0; j < 4; ++j) acc[i][j] = 0.0f;

    const int srow = tid & 63, skq = tid >> 6;
    const int grow = rt * 64 + srow;
    const bool rvalid = grow < rows;
    int hoff = 0;
    if (rvalid) {
        const int bj = grow >> 1, s = grow & 1;
        const int b = bj >> nshift, j = bj & (n - 1);
        const int node = first + j;
        hoff = (b * N_ + 2 * node + 1 + s) * H_;
    }
    const int gcol = ct * 64 + srow;

    for (int kt = 0; kt < 64; ++kt) {
        const int k0 = kt << 3;
        {
            const int kg = k0 + (skq << 1);
            float2 v = make_float2(0.f, 0.f);
            if (rvalid) v = *(const float2*)(hbuf + hoff + kg);
            As[(skq << 1) + 0][srow] = v.x;
            As[(skq << 1) + 1][srow] = v.y;
        }
        {
            const int kg = k0 + (skq << 1);
            Bs[(skq << 1) + 0][srow] = Ufw[(size_t)kg * H_ + gcol];
            Bs[(skq << 1) + 1][srow] = Ufw[(size_t)(kg + 1) * H_ + gcol];
        }
        __syncthreads();
#pragma unroll
        for (int kk = 0; kk < 8; ++kk) {
            float a[4], bb[4];
            *(float4*)&a[0]  = *(const float4*)&As[kk][tr << 2];
            *(float4*)&bb[0] = *(const float4*)&Bs[kk][tc << 2];
#pragma unroll
            for (int i = 0; i < 4; ++i)
#pragma unroll
                for (int j = 0; j < 4; ++j)
                    acc[i][j] = fmaf(a[i], bb[j], acc[i][j]);
        }
        __syncthreads();
    }
#pragma unroll
    for (int p = 0; p < 2; ++p) {
        const int r0 = rt * 64 + (tr << 2) + 2 * p;
        if (r0 < rows) {
            const int bj = r0 >> 1;
            const int b = bj >> nshift, j = bj & (n - 1);
            const int node = first + j;
            const float* c1 = cbuf + (b * N_ + 2 * node + 1) * H_ + ct * 64;
            const float* c2 = c1 + H_;
            float* dst = cagg + bj * H_ + ct * 64;
            const int off = tc << 2;
            float4 cc1 = *(const float4*)(c1 + off);
            float4 cc2 = *(const float4*)(c2 + off);
            float4 bbv = *(const float4*)(Ufb + ct * 64 + off);
            float4 res;
            res.x = sigf(acc[2*p][0] + bbv.x) * cc1.x + sigf(acc[2*p+1][0] + bbv.x) * cc2.x;
            res.y = sigf(acc[2*p][1] + bbv.y) * cc1.y + sigf(acc[2*p+1][1] + bbv.y) * cc2.y;
            res.z = sigf(acc[2*p][2] + bbv.z) * cc1.z + sigf(acc[2*p+1][2] + bbv.z) * cc2.z;
            res.w = sigf(acc[2*p][3] + bbv.w) * cc1.w + sigf(acc[2*p+1][3] + bbv.w) * cc2.w;
            *(float4*)(dst + off) = res;
        }
    }
}

// merged fagg+iou, small internal levels (n<=64)
__global__ void __launch_bounds__(256)
tree_small_k(const int* __restrict__ node_feat, const int* __restrict__ mask,
             const float* __restrict__ emb, const float* __restrict__ Wiou,
             const float* __restrict__ Uiou, const float* __restrict__ hbuf,
             const float* __restrict__ cbuf, const float* __restrict__ Ufw,
             const float* __restrict__ Ufb, float* __restrict__ cagg,
             float* __restrict__ iou_out, int first, int n, int nshift)
{
    __shared__ __align__(16) float As[8][72];
    __shared__ __align__(16) float Bs[8][72];
    const int nf_rt = n;                 // fagg row-tiles (64 rows each)
    const int Nf    = nf_rt << 3;        // x8 col tiles
    const int bid   = blockIdx.x;
    if (bid < Nf) {
        fagg_small_body(hbuf, cbuf, Ufw, Ufb, cagg, first, n, nshift,
                        bid % nf_rt, bid / nf_rt, As, Bs);
    } else {
        const int b2 = bid - Nf;
        const int ni_rt = (n >= 2) ? (n >> 1) : 1;
        iou_small_body(node_feat, mask, emb, Wiou, Uiou, hbuf, iou_out,
                       first, n, nshift, b2 % ni_rt, b2 / ni_rt, As, Bs);
    }
}

// ---------------------------------------------------------------------------
// apply_node (all levels)
// ---------------------------------------------------------------------------
template<bool LEAF>
__global__ void apply_node_k(const float* __restrict__ iou,
                             const float* __restrict__ b_iou,
                             const float* __restrict__ cagg,
                             float* __restrict__ hbuf, float* __restrict__ cbuf,
                             int first, int n, int nshift)
{
    const int gid = blockIdx.x * 256 + threadIdx.x;
    if (gid >= B_ * n * 128) return;
    const int r = gid >> 7, col = (gid & 127) << 2;
    const float* row = iou + (size_t)r * 1536;
    float4 iv = *(const float4*)(row + col);
    float4 ov = *(const float4*)(row + 512 + col);
    float4 uv = *(const float4*)(row + 1024 + col);
    float4 bi = *(const float4*)(b_iou + col);
    float4 bo = *(const float4*)(b_iou + 512 + col);
    float4 bu = *(const float4*)(b_iou + 1024 + col);
    float4 ca = make_float4(0.f, 0.f, 0.f, 0.f);
    if (!LEAF) ca = *(const float4*)(cagg + r * H_ + col);
    float4 cn, hn;
    cn.x = sigf(iv.x + bi.x) * tanhf(uv.x + bu.x) + ca.x;
    cn.y = sigf(iv.y + bi.y) * tanhf(uv.y + bu.y) + ca.y;
    cn.z = sigf(iv.z + bi.z) * tanhf(uv.z + bu.z) + ca.z;
    cn.w = sigf(iv.w + bi.w) * tanhf(uv.w + bu.w) + ca.w;
    hn.x = sigf(ov.x + bo.x) * tanhf(cn.x);
    hn.y = sigf(ov.y + bo.y) * tanhf(cn.y);
    hn.z = sigf(ov.z + bo.z) * tanhf(cn.z);
    hn.w = sigf(ov.w + bo.w) * tanhf(cn.w);
    const int b = r >> nshift, j = r & (n - 1);
    const int node = first + j;
    const size_t o = (size_t)(b * N_ + node) * H_ + col;
    *(float4*)(cbuf + o) = cn;
    *(float4*)(hbuf + o) = hn;
}

// ---------------------------------------------------------------------------
// two-stage mean over nodes
// ---------------------------------------------------------------------------
__global__ void mean_part_k(const float* __restrict__ hbuf, float* __restrict__ mpart)
{
    const int bid = blockIdx.x;               // 256 = 32 b x 8 chunks
    const int b = bid >> 3, chunk = bid & 7;
    const int tid = threadIdx.x;
    const int n0 = chunk * 128;
    const int n1 = (n0 + 128 < N_) ? (n0 + 128) : N_;
    float s0 = 0.f, s1 = 0.f;
    for (int nn = n0; nn < n1; ++nn) {
        const float* p = hbuf + (size_t)(b * N_ + nn) * H_;
        s0 += p[tid];
        s1 += p[tid + 256];
    }
    mpart[(bid << 9) + tid]       = s0;
    mpart[(bid << 9) + tid + 256] = s1;
}

__global__ void mean_fin_k(const float* __restrict__ mpart, float* __restrict__ mf)
{
    const int gid = blockIdx.x * 256 + threadIdx.x;   // 16384
    const int b = gid >> 9, k = gid & 511;
    float s = 0.f;
#pragma unroll
    for (int c = 0; c < 8; ++c) s += mpart[(((b << 3) + c) << 9) + k];
    mf[gid] = s * (1.0f / 1023.0f);
}

__global__ void hidcel_k(const float* __restrict__ mf,
                         const float* __restrict__ hw, const float* __restrict__ hb,
                         const float* __restrict__ cw, const float* __restrict__ cb,
                         float* __restrict__ hs0, float* __restrict__ cs)
{
    const int gid = blockIdx.x * 256 + threadIdx.x;   // 32768
    const int which = gid >> 14;
    const int b = (gid >> 9) & 31, l = gid & 511;
    const float* W = which ? cw : hw;
    float acc = which ? cb[l] : hb[l];
#pragma unroll 8
    for (int k = 0; k < H_; ++k) acc = fmaf(mf[b * H_ + k], W[k * H_ + l], acc);
    if (which) cs[b * H_ + l] = acc; else hs0[b * H_ + l] = acc;
}

// ---------------------------------------------------------------------------
// gate-weight transpose: Wt[g][k] (g in [0,2048), k in [0,768))
// ---------------------------------------------------------------------------
__global__ void __launch_bounds__(256)
wtrans_k(const float* __restrict__ W_ih, const float* __restrict__ W_hh,
         float* __restrict__ Wt)
{
    __shared__ float t[64][33];
    const int k0 = blockIdx.x * 32;   // 24 k-tiles
    const int g0 = blockIdx.y * 64;   // 32 g-tiles
    const int tid = threadIdx.x;
    for (int idx = tid; idx < 2048; idx += 256) {
        const int kk = idx >> 6, gg = idx & 63;
        const int k = k0 + kk;
        t[gg][kk] = (k < E_) ? W_ih[(size_t)k * 2048 + g0 + gg]
                             : W_hh[(size_t)(k - E_) * 2048 + g0 + gg];
    }
    __syncthreads();
    for (int idx = tid; idx < 2048; idx += 256) {
        const int gg = idx >> 5, kk = idx & 31;
        Wt[(size_t)(g0 + gg) * 768 + k0 + kk] = t[gg][kk];
    }
}

// ---------------------------------------------------------------------------
// decoder LSTM step v6 (R11 proven): transposed Wt, float4 k-sweeps.
// ---------------------------------------------------------------------------
__global__ void __launch_bounds__(256)
lstm_step_k(const float* __restrict__ emb, const float* __restrict__ Wt,
            const float* __restrict__ b_ih, const float* __restrict__ b_hh,
            const float* __restrict__ pval, const int* __restrict__ pidx,
            const float* __restrict__ hs_in, float* __restrict__ hs_out,
            float* __restrict__ cs, int t)
{
    __shared__ __align__(16) float xh[8][776];       // 24.8 KB
    __shared__ __align__(16) float part[4][8][8][4]; // 4 KB
    __shared__ float rv[256];
    __shared__ int   ri[256];
    __shared__ int   tokS[8];
    const int tid = threadIdx.x;
    const int bg  = blockIdx.y;          // b-group (8 batches)

    if (t == 1) {
        if (tid < 8) tokS[tid] = 0;
    } else {
        const int bs = tid >> 5, th = tid & 31;     // 8 b x 32 scanners
        const int b = bg * 8 + bs;
        float bv = -INFINITY; int bi = 0x7fffffff;
        for (int p = th; p < NBL; p += 32) {
            const float v = pval[b * NBL + p];
            const int  ix = pidx[b * NBL + p];
            if (v > bv || (v == bv && ix < bi)) { bv = v; bi = ix; }
        }
        rv[tid] = bv; ri[tid] = bi;
        __syncthreads();
        if (tid < 8) {
            float Bv = -INFINITY; int Bi = 0x7fffffff;
#pragma unroll
            for (int c = 0; c < 32; ++c) {
                const float v = rv[tid * 32 + c];
                const int  ix = ri[tid * 32 + c];
                if (v > Bv || (v == Bv && ix < Bi)) { Bv = v; Bi = ix; }
            }
            tokS[tid] = Bi;
        }
    }
    __syncthreads();

    for (int idx = tid; idx < 8 * E_; idx += 256) {
        const int b = idx >> 8, k = idx & 255;
        xh[b][k] = emb[(size_t)tokS[b] * E_ + k];
    }
    for (int idx = tid; idx < 8 * H_; idx += 256) {
        const int b = idx >> 9, k = idx & 511;
        xh[b][E_ + k] = hs_in[(size_t)(bg * 8 + b) * H_ + k];
    }
    __syncthreads();

    const int ks = tid >> 6;
    const int lane = tid & 63;
    const int bi = lane >> 3, li = lane & 7;
    const int l = blockIdx.x * 8 + li;
    float ai = 0.f, af = 0.f, ag = 0.f, ao = 0.f;
    const int k0 = ks * 192;
    const float* wi = Wt + (size_t)(l)        * 768 + k0;
    const float* wf = Wt + (size_t)(512 + l)  * 768 + k0;
    const float* wg = Wt + (size_t)(1024 + l) * 768 + k0;
    const float* wo = Wt + (size_t)(1536 + l) * 768 + k0;
    const float* xp = &xh[bi][k0];
#pragma unroll 4
    for (int kk = 0; kk < 192; kk += 4) {
        const float4 xv = *(const float4*)(xp + kk);
        const float4 w0 = *(const float4*)(wi + kk);
        const float4 w1 = *(const float4*)(wf + kk);
        const float4 w2 = *(const float4*)(wg + kk);
        const float4 w3 = *(const float4*)(wo + kk);
        ai = fmaf(xv.x, w0.x, ai); ai = fmaf(xv.y, w0.y, ai);
        ai = fmaf(xv.z, w0.z, ai); ai = fmaf(xv.w, w0.w, ai);
        af = fmaf(xv.x, w1.x, af); af = fmaf(xv.y, w1.y, af);
        af = fmaf(xv.z, w1.z, af); af = fmaf(xv.w, w1.w, af);
        ag = fmaf(xv.x, w2.x, ag); ag = fmaf(xv.y, w2.y, ag);
        ag = fmaf(xv.z, w2.z, ag); ag = fmaf(xv.w, w2.w, ag);
        ao = fmaf(xv.x, w3.x, ao); ao = fmaf(xv.y, w3.y, ao);
        ao = fmaf(xv.z, w3.z, ao); ao = fmaf(xv.w, w3.w, ao);
    }
    part[ks][bi][li][0] = ai;
    part[ks][bi][li][1] = af;
    part[ks][bi][li][2] = ag;
    part[ks][bi][li][3] = ao;
    __syncthreads();

    if (tid < 64) {
        const int b2 = tid >> 3, l2i = tid & 7;
        const int l2 = blockIdx.x * 8 + l2i;
        const int b = bg * 8 + b2;
        float s0 = 0.f, s1 = 0.f, s2 = 0.f, s3 = 0.f;
#pragma unroll
        for (int q = 0; q < 4; ++q) {
            s0 += part[q][b2][l2i][0];
            s1 += part[q][b2][l2i][1];
            s2 += part[q][b2][l2i][2];
            s3 += part[q][b2][l2i][3];
        }
        const float gi = s0 + b_ih[l2]        + b_hh[l2];
        const float gf = s1 + b_ih[512 + l2]  + b_hh[512 + l2];
        const float gg = s2 + b_ih[1024 + l2] + b_hh[1024 + l2];
        const float go = s3 + b_ih[1536 + l2] + b_hh[1536 + l2];
        const float co = cs[b * H_ + l2];
        const float cn = sigf(gf) * co + sigf(gi) * tanhf(gg);
        cs[b * H_ + l2] = cn;
        hs_out[b * H_ + l2] = sigf(go) * tanhf(cn);
    }
}

// ---------------------------------------------------------------------------
// logits partial: grid (250 col-tiles, 2 k-halves). [R5 proven]
// ---------------------------------------------------------------------------
__global__ void __launch_bounds__(256)
logits_part_k(const float* __restrict__ fc_w, const float* __restrict__ hs,
              float* __restrict__ partial)
{
    __shared__ __align__(16) float sm[256 * 36];   // 36,864 B
    const int tid = threadIdx.x;
    const int blk = blockIdx.x;       // col tile (128 cols)
    const int kh  = blockIdx.y;       // k half (256 rows)

    for (int idx = tid; idx < B_ * 256; idx += 256) {
        const int b = idx & 31, k = idx >> 5;
        sm[k * 36 + b] = hs[b * H_ + kh * 256 + k];
    }
    __syncthreads();

    const int w8   = (tid >> 6) << 3;       // wave's b-chunk: 0,8,16,24
    const int lane = tid & 63;
    const int col  = (blk << 7) + (lane << 1);

    float acc[8][2];
#pragma unroll
    for (int i = 0; i < 8; ++i) { acc[i][0] = 0.f; acc[i][1] = 0.f; }

    const float* wp = fc_w + (size_t)(kh * 256) * V_ + col;
    const float* hp = sm + w8;
    float2 wreg[8];
#pragma unroll
    for (int j = 0; j < 8; ++j) wreg[j] = *(const float2*)(wp + (size_t)j * V_);
    for (int kb = 0; kb < 32; ++kb) {
        float2 wnxt[8];
        if (kb < 31) {
            const float* wq = wp + (size_t)((kb + 1) << 3) * V_;
#pragma unroll
            for (int j = 0; j < 8; ++j) wnxt[j] = *(const float2*)(wq + (size_t)j * V_);
        }
#pragma unroll
        for (int j = 0; j < 8; ++j) {
            const float* hq = hp + ((kb << 3) + j) * 36;   // wave-uniform LDS broadcast
            float hv[8];
            *(float4*)&hv[0] = *(const float4*)(hq);
            *(float4*)&hv[4] = *(const float4*)(hq + 4);
#pragma unroll
            for (int i = 0; i < 8; ++i) {
                acc[i][0] = fmaf(hv[i], wreg[j].x, acc[i][0]);
                acc[i][1] = fmaf(hv[i], wreg[j].y, acc[i][1]);
            }
        }
        if (kb < 31) {
#pragma unroll
            for (int j = 0; j < 8; ++j) wreg[j] = wnxt[j];
        }
    }
#pragma unroll
    for (int i = 0; i < 8; ++i) {
        float* dst = partial + (size_t)(kh * B_ + w8 + i) * V_ + col;
        *(float2*)dst = make_float2(acc[i][0], acc[i][1]);
    }
}

// ---------------------------------------------------------------------------
// logits finalize: 250 blocks. sum 2 halves + bias -> out (NT stores),
// block argmax.
// ---------------------------------------------------------------------------
__global__ void __launch_bounds__(256)
logits_fin_k(const float* __restrict__ partial, const float* __restrict__ fc_b,
             float* __restrict__ out_t, float* __restrict__ pval,
             int* __restrict__ pidx)
{
    __shared__ float rv[256];
    __shared__ int   ri[256];
    const int tid = threadIdx.x, blk = blockIdx.x;
    const int b = tid >> 3, cg = (tid & 7) << 4;
    const int colbase = (blk << 7) + cg;

    const float* p0 = partial + (size_t)b * V_ + colbase;
    const float* p1 = partial + (size_t)(B_ + b) * V_ + colbase;
    const float* bp = fc_b + colbase;
    float* op = out_t + (size_t)b * V_ + colbase;

    float bv = -INFINITY; int bi = 0;
#pragma unroll
    for (int q = 0; q < 4; ++q) {
        float4 a = *(const float4*)(p0 + (q << 2));
        float4 c = *(const float4*)(p1 + (q << 2));
        float4 d = *(const float4*)(bp + (q << 2));
        float4 v;
        v.x = a.x + c.x + d.x; v.y = a.y + c.y + d.y;
        v.z = a.z + c.z + d.z; v.w = a.w + c.w + d.w;
        nt_store4(op + (q << 2), v);   // keep fc_w L3-resident
        const int c0 = cg + (q << 2);
        if (v.x > bv) { bv = v.x; bi = c0 + 0; }
        if (v.y > bv) { bv = v.y; bi = c0 + 1; }
        if (v.z > bv) { bv = v.z; bi = c0 + 2; }
        if (v.w > bv) { bv = v.w; bi = c0 + 3; }
    }
    rv[tid] = bv; ri[tid] = bi;
    __syncthreads();
    if (tid < B_) {
        float Bv = -INFINITY; int Bi = 0;
#pragma unroll
        for (int q = 0; q < 8; ++q) {
            const float v = rv[(tid << 3) + q];     // ascending col order
            if (v > Bv) { Bv = v; Bi = ri[(tid << 3) + q]; }
        }
        pval[tid * NBL + blk] = Bv;
        pidx[tid * NBL + blk] = (blk << 7) + Bi;
    }
}

// ---------------------------------------------------------------------------
extern "C" void kernel_launch(void* const* d_in, const int* in_sizes, int n_in,
                              void* d_out, int out_size, void* d_ws, size_t ws_size,
                              hipStream_t stream)
{
    (void)in_sizes; (void)n_in; (void)out_size; (void)ws_size;
    const int*   node_feat = (const int*)  d_in[0];
    const int*   mask      = (const int*)  d_in[1];
    const float* emb       = (const float*)d_in[2];
    const float* W_iou     = (const float*)d_in[3];
    const float* U_iou     = (const float*)d_in[4];
    const float* b_iou     = (const float*)d_in[5];
    const float* U_f_w     = (const float*)d_in[6];
    const float* U_f_b     = (const float*)d_in[7];
    const float* hid_fc_w  = (const float*)d_in[8];
    const float* hid_fc_b  = (const float*)d_in[9];
    const float* cell_fc_w = (const float*)d_in[10];
    const float* cell_fc_b = (const float*)d_in[11];
    const float* W_ih      = (const float*)d_in[12];
    const float* W_hh      = (const float*)d_in[13];
    const float* b_ih      = (const float*)d_in[14];
    const float* b_hh      = (const float*)d_in[15];
    const float* fc_w      = (const float*)d_in[16];
    const float* fc_b      = (const float*)d_in[17];
    float* out = (float*)d_out;

    float* ws      = (float*)d_ws;
    float* iou_buf = ws;                      // 12,582,912 (8192 x 1536)
    float* cagg    = ws + 12582912;           //  4,194,304
    float* hbuf    = ws + 16777216;           // 16,760,832
    float* cbuf    = ws + 33538048;           // 16,760,832
    float* mf      = ws + 50298880;           //     16,384
    float* hsb     = ws + 50315264;           //     32,768 (ping-pong)
    float* csb     = ws + 50348032;           //     16,384
    float* pval    = ws + 50364416;           //      8,000 (32 x 250)
    int*   pidx    = (int*)(ws + 50372416);   //      8,000
    // after the tree, iou_buf is dead -> reuse
    float* mpart   = iou_buf;                 //    131,072 floats
    float* partial = iou_buf + 262144;        //  2,048,000 floats (2 x 32 x V)
    float* Wt      = iou_buf + 2359296;       //  1,572,864 floats (2048 x 768)

    // ---- tree: leaves (2 chunks of 256 nodes) ----
    for (int chunk = 0; chunk < 2; ++chunk) {
        const int first = 511 + 256 * chunk;
        dim3 g(64, 12);
        iou_gemm_k<true><<<g, 256, 0, stream>>>(node_feat, mask, emb, W_iou, U_iou,
                                                hbuf, iou_buf, first, 256, 8);
        apply_node_k<true><<<4096, 256, 0, stream>>>(iou_buf, b_iou, cagg,
                                                     hbuf, cbuf, first, 256, 8);
    }
    // ---- tree: internal levels ----
    for (int d = 8; d >= 0; --d) {
        const int n = 1 << d, first = n - 1;
        if (n >= 128) {
            // big levels: separate proven kernels (60 VGPR, 27% occupancy)
            dim3 gf((64 * n + 127) / 128, 4);
            fagg_gemm_k<<<gf, 256, 0, stream>>>(hbuf, cbuf, U_f_w, U_f_b, cagg, first, n, d);
            dim3 gi((32 * n + 127) / 128, 12);
            iou_gemm_k<false><<<gi, 256, 0, stream>>>(node_feat, mask, emb, W_iou, U_iou,
                                                      hbuf, iou_buf, first, n, d);
        } else {
            // small levels: merged single dispatch (latency-floor, concurrency wins)
            const int ni_rt = (n >= 2) ? (n >> 1) : 1;
            const int nb = n * 8 + ni_rt * 24;
            tree_small_k<<<nb, 256, 0, stream>>>(node_feat, mask, emb, W_iou, U_iou,
                                                 hbuf, cbuf, U_f_w, U_f_b, cagg,
                                                 iou_buf, first, n, d);
        }
        apply_node_k<false><<<16 * n, 256, 0, stream>>>(iou_buf, b_iou, cagg,
                                                        hbuf, cbuf, first, n, d);
    }
    // ---- pool + init + gate-weight transpose (iou_buf dead from here) ----
    mean_part_k<<<256, 256, 0, stream>>>(hbuf, mpart);
    mean_fin_k<<<64, 256, 0, stream>>>(mpart, mf);
    hidcel_k<<<128, 256, 0, stream>>>(mf, hid_fc_w, hid_fc_b, cell_fc_w, cell_fc_b, hsb, csb);
    dim3 gw(24, 32);
    wtrans_k<<<gw, 256, 0, stream>>>(W_ih, W_hh, Wt);
    // ---- out[0] = 0 ----
    hipMemsetAsync(d_out, 0, (size_t)B_ * V_ * sizeof(float), stream);
    // ---- decoder: 3 kernels per step ----
    for (int t = 1; t < T_; ++t) {
        const float* hs_in  = hsb + ((t - 1) & 1) * (B_ * H_);
        float*       hs_out = hsb + (t & 1) * (B_ * H_);
        dim3 gl(64, 4);
        lstm_step_k<<<gl, 256, 0, stream>>>(emb, Wt, b_ih, b_hh,
                                            pval, pidx, hs_in, hs_out, csb, t);
        dim3 gp(NBL, 2);
        logits_part_k<<<gp, 256, 0, stream>>>(fc_w, hs_out, partial);
        logits_fin_k<<<NBL, 256, 0, stream>>>(partial, fc_b,
                                              out + (size_t)t * B_ * V_, pval, pidx);
    }
}